// Round 3
// baseline (87.434 us; speedup 1.0000x reference)
//
#include <hip/hip_runtime.h>
#include <stdint.h>

#define K_DIM 1024
#define M_TOT 16384
#define BM 128
#define BN 128
#define BK 64

typedef __attribute__((ext_vector_type(8))) short bf16x8;
typedef __attribute__((ext_vector_type(4))) float f32x4;
typedef __attribute__((ext_vector_type(8))) unsigned short u16x8;

__device__ inline uint16_t f2bf(float f) {
    union { float f; uint32_t u; } v; v.f = f;
    return (uint16_t)((v.u + 0x7fffu + ((v.u >> 16) & 1u)) >> 16);
}

// ---- x (16M f32) -> bf16, vectorized ----
__global__ void cvt_x_kernel(const float* __restrict__ x, uint16_t* __restrict__ xb) {
    const size_t n8 = (size_t)M_TOT * K_DIM / 8;
    for (size_t i = (size_t)blockIdx.x * blockDim.x + threadIdx.x; i < n8;
         i += (size_t)gridDim.x * blockDim.x) {
        const float4* s = (const float4*)x + i * 2;
        float4 a = s[0], b = s[1];
        u16x8 v;
        v[0] = f2bf(a.x); v[1] = f2bf(a.y); v[2] = f2bf(a.z); v[3] = f2bf(a.w);
        v[4] = f2bf(b.x); v[5] = f2bf(b.y); v[6] = f2bf(b.z); v[7] = f2bf(b.w);
        *(u16x8*)(xb + i * 8) = v;
    }
}

// ---- real-only weights: Wc[k][s] = cos(2*pi*k*s/N), bf16 [1024][1024] ----
__global__ void build_wc_kernel(const float* __restrict__ wcos, uint16_t* __restrict__ W) {
    int i = blockIdx.x * blockDim.x + threadIdx.x;   // 131072 threads, 8 elems each
    int k = i >> 7;
    int sc = (i & 127) * 8;
    const float4* c = (const float4*)(wcos + (size_t)k * K_DIM + sc);
    float4 c0 = c[0], c1 = c[1];
    u16x8 vc;
    vc[0] = f2bf(c0.x); vc[1] = f2bf(c0.y); vc[2] = f2bf(c0.z); vc[3] = f2bf(c0.w);
    vc[4] = f2bf(c1.x); vc[5] = f2bf(c1.y); vc[6] = f2bf(c1.z); vc[7] = f2bf(c1.w);
    *(u16x8*)(W + (size_t)k * K_DIM + sc) = vc;
}

// ---- interleaved weights: W[2k][s]=cos, W[2k+1][s]=-sin (complex64 layout) ----
__global__ void build_w_kernel(const float* __restrict__ wsin, const float* __restrict__ wcos,
                               uint16_t* __restrict__ W) {
    int i = blockIdx.x * blockDim.x + threadIdx.x;
    int k = i >> 7;
    int sc = (i & 127) * 8;
    const float4* c = (const float4*)(wcos + (size_t)k * K_DIM + sc);
    const float4* s = (const float4*)(wsin + (size_t)k * K_DIM + sc);
    float4 c0 = c[0], c1 = c[1], s0 = s[0], s1 = s[1];
    u16x8 vc, vs;
    vc[0] = f2bf(c0.x); vc[1] = f2bf(c0.y); vc[2] = f2bf(c0.z); vc[3] = f2bf(c0.w);
    vc[4] = f2bf(c1.x); vc[5] = f2bf(c1.y); vc[6] = f2bf(c1.z); vc[7] = f2bf(c1.w);
    vs[0] = f2bf(-s0.x); vs[1] = f2bf(-s0.y); vs[2] = f2bf(-s0.z); vs[3] = f2bf(-s0.w);
    vs[4] = f2bf(-s1.x); vs[5] = f2bf(-s1.y); vs[6] = f2bf(-s1.z); vs[7] = f2bf(-s1.w);
    *(u16x8*)(W + (size_t)(2 * k) * K_DIM + sc) = vc;
    *(u16x8*)(W + (size_t)(2 * k + 1) * K_DIM + sc) = vs;
}

// ---- bf16 MFMA GEMM (reg-staged LDS): C[M][NDIM] = A[M][K] * B[NDIM][K]^T ----
template <int NDIM>
__global__ __launch_bounds__(256) void dft_gemm(const uint16_t* __restrict__ A,
                                                const uint16_t* __restrict__ B,
                                                float* __restrict__ C,
                                                long long out_elems) {
    constexpr int NT = NDIM / BN;   // n-tiles
    __shared__ uint16_t As[BM * BK];
    __shared__ uint16_t Bs[BN * BK];

    const int t = threadIdx.x;
    const int l = t & 63;
    const int w = t >> 6;

    const int bid = blockIdx.x;
    const int bm = (bid / NT) * BM;
    const int bn = (bid % NT) * BN;

    const uint16_t* gA[4];
    const uint16_t* gB[4];
#pragma unroll
    for (int i = 0; i < 4; ++i) {
        int chunk = i * 256 + t;
        int row = chunk >> 3;
        int cc = (chunk & 7) * 8;
        gA[i] = A + (size_t)(bm + row) * K_DIM + cc;
        gB[i] = B + (size_t)(bn + row) * K_DIM + cc;
    }

    const int wm = ((w >> 1) & 1) * 64;
    const int wn = (w & 1) * 64;
    const int lr = l & 15;
    const int lk = (l >> 4) * 8;

    f32x4 acc[4][4] = {};

    for (int k0 = 0; k0 < K_DIM; k0 += BK) {
        u16x8 ra[4], rb[4];
#pragma unroll
        for (int i = 0; i < 4; ++i) ra[i] = *(const u16x8*)(gA[i] + k0);
#pragma unroll
        for (int i = 0; i < 4; ++i) rb[i] = *(const u16x8*)(gB[i] + k0);
        __syncthreads();
#pragma unroll
        for (int i = 0; i < 4; ++i) {
            *(u16x8*)&As[(i * 256 + t) * 8] = ra[i];
            *(u16x8*)&Bs[(i * 256 + t) * 8] = rb[i];
        }
        __syncthreads();
#pragma unroll
        for (int kk = 0; kk < BK; kk += 32) {
            bf16x8 af[4], bfr[4];
#pragma unroll
            for (int m = 0; m < 4; ++m)
                af[m] = *(const bf16x8*)&As[(wm + m * 16 + lr) * BK + kk + lk];
#pragma unroll
            for (int n = 0; n < 4; ++n)
                bfr[n] = *(const bf16x8*)&Bs[(wn + n * 16 + lr) * BK + kk + lk];
#pragma unroll
            for (int m = 0; m < 4; ++m)
#pragma unroll
                for (int n = 0; n < 4; ++n)
                    acc[m][n] = __builtin_amdgcn_mfma_f32_16x16x32_bf16(af[m], bfr[n],
                                                                        acc[m][n], 0, 0, 0);
        }
        __syncthreads();
    }

    // C/D layout (m89): col = lane&15, row = (lane>>4)*4 + j
    const int cr = (l >> 4) * 4;
    const bool safe = ((long long)(bm + BM) * NDIM) <= out_elems;
    if (safe) {
#pragma unroll
        for (int m = 0; m < 4; ++m) {
            int grow = bm + wm + m * 16 + cr;
#pragma unroll
            for (int j = 0; j < 4; ++j) {
                float* cp = C + (size_t)(grow + j) * NDIM + bn + wn + lr;
#pragma unroll
                for (int n = 0; n < 4; ++n)
                    cp[n * 16] = acc[m][n][j];
            }
        }
    } else {
        for (int m = 0; m < 4; ++m) {
            int grow = bm + wm + m * 16 + cr;
            for (int j = 0; j < 4; ++j) {
                long long base = (long long)(grow + j) * NDIM + bn + wn + lr;
                for (int n = 0; n < 4; ++n)
                    if (base + n * 16 < out_elems) C[base + n * 16] = acc[m][n][j];
            }
        }
    }
}

// ---- fp32 fallback (only if ws too small) ----
__global__ void dft_naive(const float* __restrict__ x, const float* __restrict__ wsin,
                          const float* __restrict__ wcos, float* __restrict__ out,
                          long long out_elems, int real_only) {
    __shared__ float xs[K_DIM];
    int row = blockIdx.x;
    const float* xr = x + (size_t)row * K_DIM;
    for (int i = threadIdx.x; i < K_DIM; i += blockDim.x) xs[i] = xr[i];
    __syncthreads();
    for (int k = threadIdx.x; k < K_DIM; k += blockDim.x) {
        const float* wc = wcos + (size_t)k * K_DIM;
        float re = 0.f;
        if (real_only) {
            for (int s = 0; s < K_DIM; ++s) re += xs[s] * wc[s];
            long long o = (long long)row * K_DIM + k;
            if (o < out_elems) out[o] = re;
        } else {
            const float* ws = wsin + (size_t)k * K_DIM;
            float im = 0.f;
            for (int s = 0; s < K_DIM; ++s) { re += xs[s] * wc[s]; im += xs[s] * ws[s]; }
            long long o = ((long long)row * K_DIM + k) * 2;
            if (o + 1 < out_elems) { out[o] = re; out[o + 1] = -im; }
        }
    }
}

extern "C" void kernel_launch(void* const* d_in, const int* in_sizes, int n_in,
                              void* d_out, int out_size, void* d_ws, size_t ws_size,
                              hipStream_t stream) {
    const float* x    = (const float*)d_in[0];
    const float* wsin = (const float*)d_in[1];
    const float* wcos = (const float*)d_in[2];
    float* out = (float*)d_out;

    const int real_only = (out_size == M_TOT * 1024);   // 16,777,216 -> real part only
    const size_t need = (size_t)M_TOT * K_DIM * 2 + (size_t)2048 * K_DIM * 2;

    if (ws_size >= need) {
        uint16_t* xb = (uint16_t*)d_ws;
        uint16_t* Wb = xb + (size_t)M_TOT * K_DIM;
        cvt_x_kernel<<<2048, 256, 0, stream>>>(x, xb);
        if (real_only) {
            build_wc_kernel<<<512, 256, 0, stream>>>(wcos, Wb);
            dft_gemm<1024><<<128 * 8, 256, 0, stream>>>(xb, Wb, out, (long long)out_size);
        } else {
            build_w_kernel<<<512, 256, 0, stream>>>(wsin, wcos, Wb);
            dft_gemm<2048><<<128 * 16, 256, 0, stream>>>(xb, Wb, out, (long long)out_size);
        }
    } else {
        dft_naive<<<M_TOT, 256, 0, stream>>>(x, wsin, wcos, out, (long long)out_size,
                                             real_only);
    }
}

// Round 4
// 77.264 us; speedup vs baseline: 1.1316x; 1.1316x over previous
//
#include <hip/hip_runtime.h>
#include <stdint.h>

#define K_DIM 1024
#define M_TOT 16384
#define BM 128
#define BN 128
#define BK 64

typedef __attribute__((ext_vector_type(8))) short bf16x8;
typedef __attribute__((ext_vector_type(4))) float f32x4;
typedef __attribute__((ext_vector_type(8))) unsigned short u16x8;

__device__ inline uint16_t f2bf(float f) {
    union { float f; uint32_t u; } v; v.f = f;
    return (uint16_t)((v.u + 0x7fffu + ((v.u >> 16) & 1u)) >> 16);
}

// ---- x (16M f32) -> bf16, vectorized ----
__global__ void cvt_x_kernel(const float* __restrict__ x, uint16_t* __restrict__ xb) {
    const size_t n8 = (size_t)M_TOT * K_DIM / 8;
    for (size_t i = (size_t)blockIdx.x * blockDim.x + threadIdx.x; i < n8;
         i += (size_t)gridDim.x * blockDim.x) {
        const float4* s = (const float4*)x + i * 2;
        float4 a = s[0], b = s[1];
        u16x8 v;
        v[0] = f2bf(a.x); v[1] = f2bf(a.y); v[2] = f2bf(a.z); v[3] = f2bf(a.w);
        v[4] = f2bf(b.x); v[5] = f2bf(b.y); v[6] = f2bf(b.z); v[7] = f2bf(b.w);
        *(u16x8*)(xb + i * 8) = v;
    }
}

// ---- real-only weights: Wc[k][s] = cos(2*pi*k*s/N), bf16 [1024][1024] ----
__global__ void build_wc_kernel(const float* __restrict__ wcos, uint16_t* __restrict__ W) {
    int i = blockIdx.x * blockDim.x + threadIdx.x;   // 131072 threads, 8 elems each
    int k = i >> 7;
    int sc = (i & 127) * 8;
    const float4* c = (const float4*)(wcos + (size_t)k * K_DIM + sc);
    float4 c0 = c[0], c1 = c[1];
    u16x8 vc;
    vc[0] = f2bf(c0.x); vc[1] = f2bf(c0.y); vc[2] = f2bf(c0.z); vc[3] = f2bf(c0.w);
    vc[4] = f2bf(c1.x); vc[5] = f2bf(c1.y); vc[6] = f2bf(c1.z); vc[7] = f2bf(c1.w);
    *(u16x8*)(W + (size_t)k * K_DIM + sc) = vc;
}

// ---- interleaved weights: W[2k][s]=cos, W[2k+1][s]=-sin (complex64 layout) ----
__global__ void build_w_kernel(const float* __restrict__ wsin, const float* __restrict__ wcos,
                               uint16_t* __restrict__ W) {
    int i = blockIdx.x * blockDim.x + threadIdx.x;
    int k = i >> 7;
    int sc = (i & 127) * 8;
    const float4* c = (const float4*)(wcos + (size_t)k * K_DIM + sc);
    const float4* s = (const float4*)(wsin + (size_t)k * K_DIM + sc);
    float4 c0 = c[0], c1 = c[1], s0 = s[0], s1 = s[1];
    u16x8 vc, vs;
    vc[0] = f2bf(c0.x); vc[1] = f2bf(c0.y); vc[2] = f2bf(c0.z); vc[3] = f2bf(c0.w);
    vc[4] = f2bf(c1.x); vc[5] = f2bf(c1.y); vc[6] = f2bf(c1.z); vc[7] = f2bf(c1.w);
    vs[0] = f2bf(-s0.x); vs[1] = f2bf(-s0.y); vs[2] = f2bf(-s0.z); vs[3] = f2bf(-s0.w);
    vs[4] = f2bf(-s1.x); vs[5] = f2bf(-s1.y); vs[6] = f2bf(-s1.z); vs[7] = f2bf(-s1.w);
    *(u16x8*)(W + (size_t)(2 * k) * K_DIM + sc) = vc;
    *(u16x8*)(W + (size_t)(2 * k + 1) * K_DIM + sc) = vs;
}

// ---- bf16 MFMA GEMM (global_load_lds staging + XCD swizzle) ----
// C[M][NDIM] = A[M][K] * B[NDIM][K]^T
template <int NDIM>
__global__ __launch_bounds__(256) void dft_gemm(const uint16_t* __restrict__ A,
                                                const uint16_t* __restrict__ B,
                                                float* __restrict__ C,
                                                long long out_elems) {
    constexpr int NT = NDIM / BN;   // n-tiles
    __shared__ uint16_t As[BM * BK];
    __shared__ uint16_t Bs[BN * BK];

    const int t = threadIdx.x;
    const int l = t & 63;
    const int w = t >> 6;

    // T1: bijective XCD swizzle (nwg % 8 == 0 for both paths)
    int bid = blockIdx.x;
    {
        int nwg = gridDim.x;
        if ((nwg & 7) == 0) {
            int q = nwg >> 3;
            bid = (bid & 7) * q + (bid >> 3);
        }
    }
    const int bm = (bid / NT) * BM;
    const int bn = (bid % NT) * BN;

    // staging: 1024 16B-chunks per 128x64 tile; 256 threads x 4 chunks each.
    // LDS dest is wave-uniform base + lane*16 (global_load_lds semantics).
    const uint16_t* gA[4];
    const uint16_t* gB[4];
    int ldsOff[4];
#pragma unroll
    for (int i = 0; i < 4; ++i) {
        int chunk = i * 256 + t;
        int row = chunk >> 3;
        int cc = (chunk & 7) * 8;
        gA[i] = A + (size_t)(bm + row) * K_DIM + cc;
        gB[i] = B + (size_t)(bn + row) * K_DIM + cc;
        ldsOff[i] = (i * 256 + (t & 192)) * 16;   // wave-uniform; HW adds lane*16
    }

    const int wm = ((w >> 1) & 1) * 64;
    const int wn = (w & 1) * 64;
    const int lr = l & 15;
    const int lk = (l >> 4) * 8;

    f32x4 acc[4][4] = {};

    for (int k0 = 0; k0 < K_DIM; k0 += BK) {
#pragma unroll
        for (int i = 0; i < 4; ++i)
            __builtin_amdgcn_global_load_lds(
                (const __attribute__((address_space(1))) void*)(gA[i] + k0),
                (__attribute__((address_space(3))) void*)((char*)As + ldsOff[i]), 16, 0, 0);
#pragma unroll
        for (int i = 0; i < 4; ++i)
            __builtin_amdgcn_global_load_lds(
                (const __attribute__((address_space(1))) void*)(gB[i] + k0),
                (__attribute__((address_space(3))) void*)((char*)Bs + ldsOff[i]), 16, 0, 0);
        __syncthreads();   // compiler drains vmcnt(0) before s_barrier -> tile ready
#pragma unroll
        for (int kk = 0; kk < BK; kk += 32) {
            bf16x8 af[4], bfr[4];
#pragma unroll
            for (int m = 0; m < 4; ++m)
                af[m] = *(const bf16x8*)&As[(wm + m * 16 + lr) * BK + kk + lk];
#pragma unroll
            for (int n = 0; n < 4; ++n)
                bfr[n] = *(const bf16x8*)&Bs[(wn + n * 16 + lr) * BK + kk + lk];
#pragma unroll
            for (int m = 0; m < 4; ++m)
#pragma unroll
                for (int n = 0; n < 4; ++n)
                    acc[m][n] = __builtin_amdgcn_mfma_f32_16x16x32_bf16(af[m], bfr[n],
                                                                        acc[m][n], 0, 0, 0);
        }
        __syncthreads();   // all ds_reads done before next iter's gload_lds lands
    }

    // C/D layout (m89): col = lane&15, row = (lane>>4)*4 + j
    const int cr = (l >> 4) * 4;
    const bool safe = ((long long)(bm + BM) * NDIM) <= out_elems;
    if (safe) {
#pragma unroll
        for (int m = 0; m < 4; ++m) {
            int grow = bm + wm + m * 16 + cr;
#pragma unroll
            for (int j = 0; j < 4; ++j) {
                float* cp = C + (size_t)(grow + j) * NDIM + bn + wn + lr;
#pragma unroll
                for (int n = 0; n < 4; ++n)
                    cp[n * 16] = acc[m][n][j];
            }
        }
    } else {
        for (int m = 0; m < 4; ++m) {
            int grow = bm + wm + m * 16 + cr;
            for (int j = 0; j < 4; ++j) {
                long long base = (long long)(grow + j) * NDIM + bn + wn + lr;
                for (int n = 0; n < 4; ++n)
                    if (base + n * 16 < out_elems) C[base + n * 16] = acc[m][n][j];
            }
        }
    }
}

// ---- fp32 fallback (only if ws too small) ----
__global__ void dft_naive(const float* __restrict__ x, const float* __restrict__ wsin,
                          const float* __restrict__ wcos, float* __restrict__ out,
                          long long out_elems, int real_only) {
    __shared__ float xs[K_DIM];
    int row = blockIdx.x;
    const float* xr = x + (size_t)row * K_DIM;
    for (int i = threadIdx.x; i < K_DIM; i += blockDim.x) xs[i] = xr[i];
    __syncthreads();
    for (int k = threadIdx.x; k < K_DIM; k += blockDim.x) {
        const float* wc = wcos + (size_t)k * K_DIM;
        float re = 0.f;
        if (real_only) {
            for (int s = 0; s < K_DIM; ++s) re += xs[s] * wc[s];
            long long o = (long long)row * K_DIM + k;
            if (o < out_elems) out[o] = re;
        } else {
            const float* ws = wsin + (size_t)k * K_DIM;
            float im = 0.f;
            for (int s = 0; s < K_DIM; ++s) { re += xs[s] * wc[s]; im += xs[s] * ws[s]; }
            long long o = ((long long)row * K_DIM + k) * 2;
            if (o + 1 < out_elems) { out[o] = re; out[o + 1] = -im; }
        }
    }
}

extern "C" void kernel_launch(void* const* d_in, const int* in_sizes, int n_in,
                              void* d_out, int out_size, void* d_ws, size_t ws_size,
                              hipStream_t stream) {
    const float* x    = (const float*)d_in[0];
    const float* wsin = (const float*)d_in[1];
    const float* wcos = (const float*)d_in[2];
    float* out = (float*)d_out;

    const int real_only = (out_size == M_TOT * 1024);   // 16,777,216 -> real part only
    const size_t need = (size_t)M_TOT * K_DIM * 2 + (size_t)2048 * K_DIM * 2;

    if (ws_size >= need) {
        uint16_t* xb = (uint16_t*)d_ws;
        uint16_t* Wb = xb + (size_t)M_TOT * K_DIM;
        cvt_x_kernel<<<2048, 256, 0, stream>>>(x, xb);
        if (real_only) {
            build_wc_kernel<<<512, 256, 0, stream>>>(wcos, Wb);
            dft_gemm<1024><<<128 * 8, 256, 0, stream>>>(xb, Wb, out, (long long)out_size);
        } else {
            build_w_kernel<<<512, 256, 0, stream>>>(wsin, wcos, Wb);
            dft_gemm<2048><<<128 * 16, 256, 0, stream>>>(xb, Wb, out, (long long)out_size);
        }
    } else {
        dft_naive<<<M_TOT, 256, 0, stream>>>(x, wsin, wcos, out, (long long)out_size,
                                             real_only);
    }
}

// Round 5
// 60.767 us; speedup vs baseline: 1.4388x; 1.2715x over previous
//
#include <hip/hip_runtime.h>
#include <stdint.h>

#define K_DIM 1024
#define M_TOT 16384
#define BM 128
#define BN 128
#define BK 64

typedef __attribute__((ext_vector_type(8))) short bf16x8;
typedef __attribute__((ext_vector_type(4))) float f32x4;
typedef __attribute__((ext_vector_type(8))) unsigned short u16x8;

__device__ inline uint16_t f2bf(float f) {
    union { float f; uint32_t u; } v; v.f = f;
    return (uint16_t)((v.u + 0x7fffu + ((v.u >> 16) & 1u)) >> 16);
}

// ---- x (16M f32) -> bf16, vectorized ----
__global__ void cvt_x_kernel(const float* __restrict__ x, uint16_t* __restrict__ xb) {
    const size_t n8 = (size_t)M_TOT * K_DIM / 8;
    for (size_t i = (size_t)blockIdx.x * blockDim.x + threadIdx.x; i < n8;
         i += (size_t)gridDim.x * blockDim.x) {
        const float4* s = (const float4*)x + i * 2;
        float4 a = s[0], b = s[1];
        u16x8 v;
        v[0] = f2bf(a.x); v[1] = f2bf(a.y); v[2] = f2bf(a.z); v[3] = f2bf(a.w);
        v[4] = f2bf(b.x); v[5] = f2bf(b.y); v[6] = f2bf(b.z); v[7] = f2bf(b.w);
        *(u16x8*)(xb + i * 8) = v;
    }
}

// ---- real-only weights: Wc[k][s] = cos(2*pi*k*s/N), bf16 [1024][1024] ----
__global__ void build_wc_kernel(const float* __restrict__ wcos, uint16_t* __restrict__ W) {
    int i = blockIdx.x * blockDim.x + threadIdx.x;
    int k = i >> 7;
    int sc = (i & 127) * 8;
    const float4* c = (const float4*)(wcos + (size_t)k * K_DIM + sc);
    float4 c0 = c[0], c1 = c[1];
    u16x8 vc;
    vc[0] = f2bf(c0.x); vc[1] = f2bf(c0.y); vc[2] = f2bf(c0.z); vc[3] = f2bf(c0.w);
    vc[4] = f2bf(c1.x); vc[5] = f2bf(c1.y); vc[6] = f2bf(c1.z); vc[7] = f2bf(c1.w);
    *(u16x8*)(W + (size_t)k * K_DIM + sc) = vc;
}

// ---- interleaved weights: W[2k][s]=cos, W[2k+1][s]=-sin (complex64 layout) ----
__global__ void build_w_kernel(const float* __restrict__ wsin, const float* __restrict__ wcos,
                               uint16_t* __restrict__ W) {
    int i = blockIdx.x * blockDim.x + threadIdx.x;
    int k = i >> 7;
    int sc = (i & 127) * 8;
    const float4* c = (const float4*)(wcos + (size_t)k * K_DIM + sc);
    const float4* s = (const float4*)(wsin + (size_t)k * K_DIM + sc);
    float4 c0 = c[0], c1 = c[1], s0 = s[0], s1 = s[1];
    u16x8 vc, vs;
    vc[0] = f2bf(c0.x); vc[1] = f2bf(c0.y); vc[2] = f2bf(c0.z); vc[3] = f2bf(c0.w);
    vc[4] = f2bf(c1.x); vc[5] = f2bf(c1.y); vc[6] = f2bf(c1.z); vc[7] = f2bf(c1.w);
    vs[0] = f2bf(-s0.x); vs[1] = f2bf(-s0.y); vs[2] = f2bf(-s0.z); vs[3] = f2bf(-s0.w);
    vs[4] = f2bf(-s1.x); vs[5] = f2bf(-s1.y); vs[6] = f2bf(-s1.z); vs[7] = f2bf(-s1.w);
    *(u16x8*)(W + (size_t)(2 * k) * K_DIM + sc) = vc;
    *(u16x8*)(W + (size_t)(2 * k + 1) * K_DIM + sc) = vs;
}

// =====================================================================
// 256x256 deep-pipelined bf16 MFMA GEMM (T1+T2+T3/T4+T5)
//   C[M][NDIM] = A[M][K] * B[NDIM][K]^T
//   512 threads = 8 waves (2 M-groups x 4 N-groups); wave owns 128x64 of C.
//   LDS: 2 dbuf x (A 256x64 + B 256x64) bf16 = 128 KiB, linear dest for
//   global_load_lds; T2 swizzle via pre-swizzled GLOBAL source column
//   (slot ^= row&7) + same XOR on ds_read addresses (rule 21).
//   Sync: raw s_barrier + asm vmcnt(0) placed a full tile after issue.
// =====================================================================
template <int NDIM>
__global__ __launch_bounds__(512, 2) void dft_gemm256(const uint16_t* __restrict__ A,
                                                      const uint16_t* __restrict__ B,
                                                      float* __restrict__ C,
                                                      long long out_elems) {
    constexpr int BM2 = 256, BN2 = 256, BK2 = 64;
    constexpr int NT = NDIM / BN2;          // n-tiles
    constexpr int NKT = K_DIM / BK2;        // 16 K-tiles
    __shared__ uint16_t lds[2][2][BM2 * BK2];   // [dbuf][A=0/B=1][256*64]

    const int t = threadIdx.x;
    const int l = t & 63;
    const int wid = t >> 6;       // 0..7
    const int wr = wid >> 2;      // 0..1   M half
    const int wc = wid & 3;       // 0..3   N quarter
    const int lr = l & 15;
    const int lhi = l >> 4;       // 0..3
    const int xr7 = lr & 7;

    // T1: bijective XCD swizzle (grid = 256 or 512, both %8==0)
    int bid = blockIdx.x;
    {
        int nwg = gridDim.x;
        if ((nwg & 7) == 0) { int q = nwg >> 3; bid = (bid & 7) * q + (bid >> 3); }
    }
    const int bm = (bid / NT) * BM2;
    const int bn = (bid % NT) * BN2;

    // ---- staging: per thread 4 chunks A + 4 chunks B, 16 B each ----
    // chunk = i*512 + t; row = chunk>>3 (8 slots of 16B per 128-B row);
    // source column pre-swizzled: slot' = slot ^ (row & 7)  (T2, rule 21)
    const uint16_t* gA[4];
    const uint16_t* gB[4];
    int ldsOff[4];
#pragma unroll
    for (int i = 0; i < 4; ++i) {
        int chunk = i * 512 + t;
        int r = chunk >> 3, sl = chunk & 7;
        int scol = (sl ^ (r & 7)) * 8;
        gA[i] = A + (size_t)(bm + r) * K_DIM + scol;
        gB[i] = B + (size_t)(bn + r) * K_DIM + scol;
        ldsOff[i] = (i * 512 + (t & ~63)) * 16;   // bytes; wave-uniform, HW adds lane*16
    }

    f32x4 acc[8][4] = {};

    // stage K-tile kt into dbuf d (8 global_load_lds, 16 B/lane each)
    auto stage = [&](int d, int kt) {
        const int k0 = kt * BK2;
#pragma unroll
        for (int i = 0; i < 4; ++i)
            __builtin_amdgcn_global_load_lds(
                (const __attribute__((address_space(1))) void*)(gA[i] + k0),
                (__attribute__((address_space(3))) void*)((char*)&lds[d][0][0] + ldsOff[i]),
                16, 0, 0);
#pragma unroll
        for (int i = 0; i < 4; ++i)
            __builtin_amdgcn_global_load_lds(
                (const __attribute__((address_space(1))) void*)(gB[i] + k0),
                (__attribute__((address_space(3))) void*)((char*)&lds[d][1][0] + ldsOff[i]),
                16, 0, 0);
    };
    // swizzled fragment read: element = row*64 + ((slot ^ (row&7))*8)
    auto loadFrag = [&](const uint16_t* base, int row, int kk) -> bf16x8 {
        int s = (kk >> 3) + lhi;
        return *(const bf16x8*)(base + row * 64 + ((s ^ xr7) * 8));
    };

    // ---- prologue: tile 0 ----
    stage(0, 0);
    __builtin_amdgcn_sched_barrier(0);
    asm volatile("s_waitcnt vmcnt(0)" ::: "memory");
    __builtin_amdgcn_s_barrier();
    __builtin_amdgcn_sched_barrier(0);

    // ---- main loop: 4 phases of 16 MFMA per K-tile; stage t+1 at top ----
    for (int kt = 0; kt < NKT; ++kt) {
        const int c = kt & 1;
        const uint16_t* bA = &lds[c][0][0];
        const uint16_t* bB = &lds[c][1][0];
        if (kt + 1 < NKT) stage(1 - c, kt + 1);   // into buf freed by prev end-barrier
#pragma unroll
        for (int kk = 0; kk < BK2; kk += 32) {
            bf16x8 bfrag[4];
#pragma unroll
            for (int n = 0; n < 4; ++n) bfrag[n] = loadFrag(bB, wc * 64 + n * 16 + lr, kk);
            // phase: m-half 0
            {
                bf16x8 afr[4];
#pragma unroll
                for (int mm = 0; mm < 4; ++mm)
                    afr[mm] = loadFrag(bA, wr * 128 + mm * 16 + lr, kk);
                __builtin_amdgcn_s_setprio(1);
#pragma unroll
                for (int mm = 0; mm < 4; ++mm)
#pragma unroll
                    for (int nn = 0; nn < 4; ++nn)
                        acc[mm][nn] = __builtin_amdgcn_mfma_f32_16x16x32_bf16(
                            afr[mm], bfrag[nn], acc[mm][nn], 0, 0, 0);
                __builtin_amdgcn_s_setprio(0);
                __builtin_amdgcn_s_barrier();
            }
            // phase: m-half 1
            {
                bf16x8 afr[4];
#pragma unroll
                for (int mm = 0; mm < 4; ++mm)
                    afr[mm] = loadFrag(bA, wr * 128 + 64 + mm * 16 + lr, kk);
                __builtin_amdgcn_s_setprio(1);
#pragma unroll
                for (int mm = 0; mm < 4; ++mm)
#pragma unroll
                    for (int nn = 0; nn < 4; ++nn)
                        acc[4 + mm][nn] = __builtin_amdgcn_mfma_f32_16x16x32_bf16(
                            afr[mm], bfrag[nn], acc[4 + mm][nn], 0, 0, 0);
                __builtin_amdgcn_s_setprio(0);
                if (kk == 0) __builtin_amdgcn_s_barrier();
            }
        }
        // end of tile: t+1's loads (issued ~4 phases ago) must be in LDS; all
        // waves done reading buf[c] before next iter's stage overwrites it.
        __builtin_amdgcn_sched_barrier(0);
        asm volatile("s_waitcnt vmcnt(0)" ::: "memory");
        __builtin_amdgcn_s_barrier();
        __builtin_amdgcn_sched_barrier(0);
    }

    // ---- epilogue: C/D layout (m89): col = lane&15, row = (lane>>4)*4 + j ----
    // wave sub-tile: rows bm + wr*128 + m*16, cols bn + wc*64 + n*16
    const int cr = lhi * 4;
    const bool safe = ((long long)(bm + BM2) * NDIM) <= out_elems;
    if (safe) {
#pragma unroll
        for (int m = 0; m < 8; ++m) {
            int grow = bm + wr * 128 + m * 16 + cr;
#pragma unroll
            for (int j = 0; j < 4; ++j) {
                float* cp = C + (size_t)(grow + j) * NDIM + bn + wc * 64 + lr;
#pragma unroll
                for (int n = 0; n < 4; ++n)
                    cp[n * 16] = acc[m][n][j];
            }
        }
    } else {
        for (int m = 0; m < 8; ++m) {
            int grow = bm + wr * 128 + m * 16 + cr;
            for (int j = 0; j < 4; ++j) {
                long long base = (long long)(grow + j) * NDIM + bn + wc * 64 + lr;
                for (int n = 0; n < 4; ++n)
                    if (base + n * 16 < out_elems) C[base + n * 16] = acc[m][n][j];
            }
        }
    }
}

// ---- 128x128 gload_lds GEMM (kept for the interleaved/2048 path) ----
template <int NDIM>
__global__ __launch_bounds__(256) void dft_gemm128(const uint16_t* __restrict__ A,
                                                   const uint16_t* __restrict__ B,
                                                   float* __restrict__ C,
                                                   long long out_elems) {
    constexpr int NT = NDIM / BN;
    __shared__ uint16_t As[BM * BK];
    __shared__ uint16_t Bs[BN * BK];

    const int t = threadIdx.x;
    const int l = t & 63;
    const int w = t >> 6;

    int bid = blockIdx.x;
    {
        int nwg = gridDim.x;
        if ((nwg & 7) == 0) { int q = nwg >> 3; bid = (bid & 7) * q + (bid >> 3); }
    }
    const int bm = (bid / NT) * BM;
    const int bn = (bid % NT) * BN;

    const uint16_t* gA[4];
    const uint16_t* gB[4];
    int ldsOff[4];
#pragma unroll
    for (int i = 0; i < 4; ++i) {
        int chunk = i * 256 + t;
        int row = chunk >> 3;
        int cc = (chunk & 7) * 8;
        gA[i] = A + (size_t)(bm + row) * K_DIM + cc;
        gB[i] = B + (size_t)(bn + row) * K_DIM + cc;
        ldsOff[i] = (i * 256 + (t & 192)) * 16;
    }

    const int wm = ((w >> 1) & 1) * 64;
    const int wn = (w & 1) * 64;
    const int lr = l & 15;
    const int lk = (l >> 4) * 8;

    f32x4 acc[4][4] = {};

    for (int k0 = 0; k0 < K_DIM; k0 += BK) {
#pragma unroll
        for (int i = 0; i < 4; ++i)
            __builtin_amdgcn_global_load_lds(
                (const __attribute__((address_space(1))) void*)(gA[i] + k0),
                (__attribute__((address_space(3))) void*)((char*)As + ldsOff[i]), 16, 0, 0);
#pragma unroll
        for (int i = 0; i < 4; ++i)
            __builtin_amdgcn_global_load_lds(
                (const __attribute__((address_space(1))) void*)(gB[i] + k0),
                (__attribute__((address_space(3))) void*)((char*)Bs + ldsOff[i]), 16, 0, 0);
        __syncthreads();
#pragma unroll
        for (int kk = 0; kk < BK; kk += 32) {
            bf16x8 af[4], bfr[4];
#pragma unroll
            for (int m = 0; m < 4; ++m)
                af[m] = *(const bf16x8*)&As[(wm + m * 16 + lr) * BK + kk + lk];
#pragma unroll
            for (int n = 0; n < 4; ++n)
                bfr[n] = *(const bf16x8*)&Bs[(wn + n * 16 + lr) * BK + kk + lk];
#pragma unroll
            for (int m = 0; m < 4; ++m)
#pragma unroll
                for (int n = 0; n < 4; ++n)
                    acc[m][n] = __builtin_amdgcn_mfma_f32_16x16x32_bf16(af[m], bfr[n],
                                                                        acc[m][n], 0, 0, 0);
        }
        __syncthreads();
    }

    const int cr = (l >> 4) * 4;
    const bool safe = ((long long)(bm + BM) * NDIM) <= out_elems;
    if (safe) {
#pragma unroll
        for (int m = 0; m < 4; ++m) {
            int grow = bm + wm + m * 16 + cr;
#pragma unroll
            for (int j = 0; j < 4; ++j) {
                float* cp = C + (size_t)(grow + j) * NDIM + bn + wn + lr;
#pragma unroll
                for (int n = 0; n < 4; ++n)
                    cp[n * 16] = acc[m][n][j];
            }
        }
    } else {
        for (int m = 0; m < 4; ++m) {
            int grow = bm + wm + m * 16 + cr;
            for (int j = 0; j < 4; ++j) {
                long long base = (long long)(grow + j) * NDIM + bn + wn + lr;
                for (int n = 0; n < 4; ++n)
                    if (base + n * 16 < out_elems) C[base + n * 16] = acc[m][n][j];
            }
        }
    }
}

// ---- fp32 fallback (only if ws too small) ----
__global__ void dft_naive(const float* __restrict__ x, const float* __restrict__ wsin,
                          const float* __restrict__ wcos, float* __restrict__ out,
                          long long out_elems, int real_only) {
    __shared__ float xs[K_DIM];
    int row = blockIdx.x;
    const float* xr = x + (size_t)row * K_DIM;
    for (int i = threadIdx.x; i < K_DIM; i += blockDim.x) xs[i] = xr[i];
    __syncthreads();
    for (int k = threadIdx.x; k < K_DIM; k += blockDim.x) {
        const float* wc = wcos + (size_t)k * K_DIM;
        float re = 0.f;
        if (real_only) {
            for (int s = 0; s < K_DIM; ++s) re += xs[s] * wc[s];
            long long o = (long long)row * K_DIM + k;
            if (o < out_elems) out[o] = re;
        } else {
            const float* ws = wsin + (size_t)k * K_DIM;
            float im = 0.f;
            for (int s = 0; s < K_DIM; ++s) { re += xs[s] * wc[s]; im += xs[s] * ws[s]; }
            long long o = ((long long)row * K_DIM + k) * 2;
            if (o + 1 < out_elems) { out[o] = re; out[o + 1] = -im; }
        }
    }
}

extern "C" void kernel_launch(void* const* d_in, const int* in_sizes, int n_in,
                              void* d_out, int out_size, void* d_ws, size_t ws_size,
                              hipStream_t stream) {
    const float* x    = (const float*)d_in[0];
    const float* wsin = (const float*)d_in[1];
    const float* wcos = (const float*)d_in[2];
    float* out = (float*)d_out;

    const int real_only = (out_size == M_TOT * 1024);
    const size_t need = (size_t)M_TOT * K_DIM * 2 + (size_t)2048 * K_DIM * 2;

    if (ws_size >= need) {
        uint16_t* xb = (uint16_t*)d_ws;
        uint16_t* Wb = xb + (size_t)M_TOT * K_DIM;
        cvt_x_kernel<<<2048, 256, 0, stream>>>(x, xb);
        if (real_only) {
            build_wc_kernel<<<512, 256, 0, stream>>>(wcos, Wb);
            dft_gemm256<1024><<<(M_TOT / 256) * (1024 / 256), 512, 0, stream>>>(
                xb, Wb, out, (long long)out_size);
        } else {
            build_w_kernel<<<512, 256, 0, stream>>>(wsin, wcos, Wb);
            dft_gemm128<2048><<<128 * 16, 256, 0, stream>>>(xb, Wb, out, (long long)out_size);
        }
    } else {
        dft_naive<<<M_TOT, 256, 0, stream>>>(x, wsin, wcos, out, (long long)out_size,
                                             real_only);
    }
}

// Round 6
// 55.599 us; speedup vs baseline: 1.5726x; 1.0929x over previous
//
#include <hip/hip_runtime.h>
#include <stdint.h>

#define K_DIM 1024
#define M_TOT 16384
#define BM 128
#define BN 128
#define BK 64

typedef __attribute__((ext_vector_type(8))) short bf16x8;
typedef __attribute__((ext_vector_type(4))) float f32x4;
typedef __attribute__((ext_vector_type(8))) unsigned short u16x8;

__device__ inline uint16_t f2bf(float f) {
    union { float f; uint32_t u; } v; v.f = f;
    return (uint16_t)((v.u + 0x7fffu + ((v.u >> 16) & 1u)) >> 16);
}

// ---- x (16M f32) -> bf16, vectorized (only used by the 2048 fallback path) ----
__global__ void cvt_x_kernel(const float* __restrict__ x, uint16_t* __restrict__ xb) {
    const size_t n8 = (size_t)M_TOT * K_DIM / 8;
    for (size_t i = (size_t)blockIdx.x * blockDim.x + threadIdx.x; i < n8;
         i += (size_t)gridDim.x * blockDim.x) {
        const float4* s = (const float4*)x + i * 2;
        float4 a = s[0], b = s[1];
        u16x8 v;
        v[0] = f2bf(a.x); v[1] = f2bf(a.y); v[2] = f2bf(a.z); v[3] = f2bf(a.w);
        v[4] = f2bf(b.x); v[5] = f2bf(b.y); v[6] = f2bf(b.z); v[7] = f2bf(b.w);
        *(u16x8*)(xb + i * 8) = v;
    }
}

// ---- real-only weights: Wc[k][s] = cos(2*pi*k*s/N), bf16 [1024][1024] ----
__global__ void build_wc_kernel(const float* __restrict__ wcos, uint16_t* __restrict__ W) {
    int i = blockIdx.x * blockDim.x + threadIdx.x;
    int k = i >> 7;
    int sc = (i & 127) * 8;
    const float4* c = (const float4*)(wcos + (size_t)k * K_DIM + sc);
    float4 c0 = c[0], c1 = c[1];
    u16x8 vc;
    vc[0] = f2bf(c0.x); vc[1] = f2bf(c0.y); vc[2] = f2bf(c0.z); vc[3] = f2bf(c0.w);
    vc[4] = f2bf(c1.x); vc[5] = f2bf(c1.y); vc[6] = f2bf(c1.z); vc[7] = f2bf(c1.w);
    *(u16x8*)(W + (size_t)k * K_DIM + sc) = vc;
}

// ---- interleaved weights (fallback path): W[2k][s]=cos, W[2k+1][s]=-sin ----
__global__ void build_w_kernel(const float* __restrict__ wsin, const float* __restrict__ wcos,
                               uint16_t* __restrict__ W) {
    int i = blockIdx.x * blockDim.x + threadIdx.x;
    int k = i >> 7;
    int sc = (i & 127) * 8;
    const float4* c = (const float4*)(wcos + (size_t)k * K_DIM + sc);
    const float4* s = (const float4*)(wsin + (size_t)k * K_DIM + sc);
    float4 c0 = c[0], c1 = c[1], s0 = s[0], s1 = s[1];
    u16x8 vc, vs;
    vc[0] = f2bf(c0.x); vc[1] = f2bf(c0.y); vc[2] = f2bf(c0.z); vc[3] = f2bf(c0.w);
    vc[4] = f2bf(c1.x); vc[5] = f2bf(c1.y); vc[6] = f2bf(c1.z); vc[7] = f2bf(c1.w);
    vs[0] = f2bf(-s0.x); vs[1] = f2bf(-s0.y); vs[2] = f2bf(-s0.z); vs[3] = f2bf(-s0.w);
    vs[4] = f2bf(-s1.x); vs[5] = f2bf(-s1.y); vs[6] = f2bf(-s1.z); vs[7] = f2bf(-s1.w);
    *(u16x8*)(W + (size_t)(2 * k) * K_DIM + sc) = vc;
    *(u16x8*)(W + (size_t)(2 * k + 1) * K_DIM + sc) = vs;
}

// =====================================================================
// Fused-cvt 256x256 bf16 MFMA GEMM:  C[M][NDIM] = cvt(X[M][K]) * B[NDIM][K]^T
//   A-staging: reg-staged f32 loads (issued at top of tile t for t+1) ->
//     v_cvt_pk_bf16_f32 -> ds_write_b128 at write-side-swizzled addr (T14+T2).
//   B-staging: global_load_lds, pre-swizzled global source, linear LDS dest.
//   Double-buffered 128 KiB LDS; raw barriers; vmcnt(0)/lgkmcnt(0) discipline.
// =====================================================================
template <int NDIM>
__global__ __launch_bounds__(512, 2) void dft_gemm256f(const float* __restrict__ X,
                                                       const uint16_t* __restrict__ Bw,
                                                       float* __restrict__ C,
                                                       long long out_elems) {
    constexpr int BM2 = 256, BN2 = 256, BK2 = 64;
    constexpr int NT = NDIM / BN2;
    constexpr int NKT = K_DIM / BK2;
    __shared__ uint16_t lds[2][2][BM2 * BK2];   // [dbuf][A=0/B=1][256*64]

    const int t = threadIdx.x;
    const int l = t & 63;
    const int wid = t >> 6;
    const int wr = wid >> 2;      // M half
    const int wc = wid & 3;       // N quarter
    const int lr = l & 15;
    const int lhi = l >> 4;
    const int xr7 = lr & 7;

    // T1: bijective XCD swizzle (grid % 8 == 0)
    int bid = blockIdx.x;
    {
        int nwg = gridDim.x;
        if ((nwg & 7) == 0) { int q = nwg >> 3; bid = (bid & 7) * q + (bid >> 3); }
    }
    const int bm = (bid / NT) * BM2;
    const int bn = (bid % NT) * BN2;

    // chunk decomposition: thread t handles rows r0 + i*64, slot sl (8 elems)
    const int r0 = t >> 3, sl = t & 7;
    const float* gA0 = X + (size_t)(bm + r0) * K_DIM + sl * 8;                 // linear src
    const int wA0 = (r0 * 8 + (sl ^ (r0 & 7))) * 16;                           // swz LDS byte
    const uint16_t* gB0 = Bw + (size_t)(bn + r0) * K_DIM + (sl ^ (r0 & 7)) * 8; // pre-swz src
    const int ldsB0 = (t & ~63) * 16;                                          // wave-uniform

    float4 ra[4][2];

    auto loadA = [&](int kt) {
        const int k0 = kt * BK2;
#pragma unroll
        for (int i = 0; i < 4; ++i) {
            const float* p = gA0 + (size_t)i * 64 * K_DIM + k0;
            ra[i][0] = *(const float4*)p;
            ra[i][1] = *(const float4*)(p + 4);
        }
    };
    auto stageB = [&](int d, int kt) {
        const int k0 = kt * BK2;
#pragma unroll
        for (int i = 0; i < 4; ++i)
            __builtin_amdgcn_global_load_lds(
                (const __attribute__((address_space(1))) void*)(gB0 + (size_t)i * 64 * K_DIM + k0),
                (__attribute__((address_space(3))) void*)((char*)&lds[d][1][0] + ldsB0 + i * 8192),
                16, 0, 0);
    };
    auto writeA = [&](int d) {
#pragma unroll
        for (int i = 0; i < 4; ++i) {
            union { u16x8 v; uint32_t w[4]; } u;
            asm("v_cvt_pk_bf16_f32 %0, %1, %2" : "=v"(u.w[0]) : "v"(ra[i][0].x), "v"(ra[i][0].y));
            asm("v_cvt_pk_bf16_f32 %0, %1, %2" : "=v"(u.w[1]) : "v"(ra[i][0].z), "v"(ra[i][0].w));
            asm("v_cvt_pk_bf16_f32 %0, %1, %2" : "=v"(u.w[2]) : "v"(ra[i][1].x), "v"(ra[i][1].y));
            asm("v_cvt_pk_bf16_f32 %0, %1, %2" : "=v"(u.w[3]) : "v"(ra[i][1].z), "v"(ra[i][1].w));
            *(u16x8*)((char*)&lds[d][0][0] + wA0 + i * 8192) = u.v;
        }
    };
    // swizzled fragment read: element = row*64 + ((slot ^ (row&7))*8)
    auto loadFrag = [&](const uint16_t* base, int row, int kk) -> bf16x8 {
        int s = (kk >> 3) + lhi;
        return *(const bf16x8*)(base + row * 64 + ((s ^ xr7) * 8));
    };

    f32x4 acc[8][4] = {};

    // ---- prologue: tile 0 ----
    loadA(0);
    stageB(0, 0);
    __builtin_amdgcn_sched_barrier(0);
    asm volatile("s_waitcnt vmcnt(0)" ::: "memory");
    __builtin_amdgcn_sched_barrier(0);
    writeA(0);
    asm volatile("s_waitcnt lgkmcnt(0)" ::: "memory");
    __builtin_amdgcn_s_barrier();
    __builtin_amdgcn_sched_barrier(0);

    // ---- main loop ----
    for (int kt = 0; kt < NKT; ++kt) {
        const int c = kt & 1;
        const uint16_t* bA = &lds[c][0][0];
        const uint16_t* bB = &lds[c][1][0];
        if (kt + 1 < NKT) { loadA(kt + 1); stageB(1 - c, kt + 1); }   // issue-early (T14)
        __builtin_amdgcn_sched_barrier(0);
#pragma unroll
        for (int kk = 0; kk < BK2; kk += 32) {
            bf16x8 bfrag[4];
#pragma unroll
            for (int n = 0; n < 4; ++n) bfrag[n] = loadFrag(bB, wc * 64 + n * 16 + lr, kk);
            // phase: m-half 0
            {
                bf16x8 afr[4];
#pragma unroll
                for (int mm = 0; mm < 4; ++mm)
                    afr[mm] = loadFrag(bA, wr * 128 + mm * 16 + lr, kk);
                __builtin_amdgcn_s_setprio(1);
#pragma unroll
                for (int mm = 0; mm < 4; ++mm)
#pragma unroll
                    for (int nn = 0; nn < 4; ++nn)
                        acc[mm][nn] = __builtin_amdgcn_mfma_f32_16x16x32_bf16(
                            afr[mm], bfrag[nn], acc[mm][nn], 0, 0, 0);
                __builtin_amdgcn_s_setprio(0);
                __builtin_amdgcn_s_barrier();
            }
            // phase: m-half 1
            {
                bf16x8 afr[4];
#pragma unroll
                for (int mm = 0; mm < 4; ++mm)
                    afr[mm] = loadFrag(bA, wr * 128 + 64 + mm * 16 + lr, kk);
                __builtin_amdgcn_s_setprio(1);
#pragma unroll
                for (int mm = 0; mm < 4; ++mm)
#pragma unroll
                    for (int nn = 0; nn < 4; ++nn)
                        acc[4 + mm][nn] = __builtin_amdgcn_mfma_f32_16x16x32_bf16(
                            afr[mm], bfrag[nn], acc[4 + mm][nn], 0, 0, 0);
                __builtin_amdgcn_s_setprio(0);
                if (kk == 0) __builtin_amdgcn_s_barrier();
            }
        }
        __builtin_amdgcn_sched_barrier(0);
        if (kt + 1 < NKT) {
            asm volatile("s_waitcnt vmcnt(0)" ::: "memory");   // A regs + B lds landed
            __builtin_amdgcn_sched_barrier(0);
            writeA(1 - c);                                     // into buf freed last barrier
        }
        asm volatile("s_waitcnt lgkmcnt(0)" ::: "memory");     // ds_writes visible
        __builtin_amdgcn_s_barrier();
        __builtin_amdgcn_sched_barrier(0);
    }

    // ---- epilogue: C/D layout (m89): col = lane&15, row = (lane>>4)*4 + j ----
    const int cr = lhi * 4;
    const bool safe = ((long long)(bm + BM2) * NDIM) <= out_elems;
    if (safe) {
#pragma unroll
        for (int m = 0; m < 8; ++m) {
            int grow = bm + wr * 128 + m * 16 + cr;
#pragma unroll
            for (int j = 0; j < 4; ++j) {
                float* cp = C + (size_t)(grow + j) * NDIM + bn + wc * 64 + lr;
#pragma unroll
                for (int n = 0; n < 4; ++n)
                    cp[n * 16] = acc[m][n][j];
            }
        }
    } else {
        for (int m = 0; m < 8; ++m) {
            int grow = bm + wr * 128 + m * 16 + cr;
            for (int j = 0; j < 4; ++j) {
                long long base = (long long)(grow + j) * NDIM + bn + wc * 64 + lr;
                for (int n = 0; n < 4; ++n)
                    if (base + n * 16 < out_elems) C[base + n * 16] = acc[m][n][j];
            }
        }
    }
}

// ---- 128x128 gload_lds GEMM (fallback for the interleaved/2048 path) ----
template <int NDIM>
__global__ __launch_bounds__(256) void dft_gemm128(const uint16_t* __restrict__ A,
                                                   const uint16_t* __restrict__ B,
                                                   float* __restrict__ C,
                                                   long long out_elems) {
    constexpr int NT = NDIM / BN;
    __shared__ uint16_t As[BM * BK];
    __shared__ uint16_t Bs[BN * BK];

    const int t = threadIdx.x;
    const int l = t & 63;
    const int w = t >> 6;

    int bid = blockIdx.x;
    {
        int nwg = gridDim.x;
        if ((nwg & 7) == 0) { int q = nwg >> 3; bid = (bid & 7) * q + (bid >> 3); }
    }
    const int bm = (bid / NT) * BM;
    const int bn = (bid % NT) * BN;

    const uint16_t* gA[4];
    const uint16_t* gB[4];
    int ldsOff[4];
#pragma unroll
    for (int i = 0; i < 4; ++i) {
        int chunk = i * 256 + t;
        int row = chunk >> 3;
        int cc = (chunk & 7) * 8;
        gA[i] = A + (size_t)(bm + row) * K_DIM + cc;
        gB[i] = B + (size_t)(bn + row) * K_DIM + cc;
        ldsOff[i] = (i * 256 + (t & 192)) * 16;
    }

    const int wm = ((w >> 1) & 1) * 64;
    const int wn = (w & 1) * 64;
    const int lr = l & 15;
    const int lk = (l >> 4) * 8;

    f32x4 acc[4][4] = {};

    for (int k0 = 0; k0 < K_DIM; k0 += BK) {
#pragma unroll
        for (int i = 0; i < 4; ++i)
            __builtin_amdgcn_global_load_lds(
                (const __attribute__((address_space(1))) void*)(gA[i] + k0),
                (__attribute__((address_space(3))) void*)((char*)As + ldsOff[i]), 16, 0, 0);
#pragma unroll
        for (int i = 0; i < 4; ++i)
            __builtin_amdgcn_global_load_lds(
                (const __attribute__((address_space(1))) void*)(gB[i] + k0),
                (__attribute__((address_space(3))) void*)((char*)Bs + ldsOff[i]), 16, 0, 0);
        __syncthreads();
#pragma unroll
        for (int kk = 0; kk < BK; kk += 32) {
            bf16x8 af[4], bfr[4];
#pragma unroll
            for (int m = 0; m < 4; ++m)
                af[m] = *(const bf16x8*)&As[(wm + m * 16 + lr) * BK + kk + lk];
#pragma unroll
            for (int n = 0; n < 4; ++n)
                bfr[n] = *(const bf16x8*)&Bs[(wn + n * 16 + lr) * BK + kk + lk];
#pragma unroll
            for (int m = 0; m < 4; ++m)
#pragma unroll
                for (int n = 0; n < 4; ++n)
                    acc[m][n] = __builtin_amdgcn_mfma_f32_16x16x32_bf16(af[m], bfr[n],
                                                                        acc[m][n], 0, 0, 0);
        }
        __syncthreads();
    }

    const int cr = (l >> 4) * 4;
    const bool safe = ((long long)(bm + BM) * NDIM) <= out_elems;
    if (safe) {
#pragma unroll
        for (int m = 0; m < 4; ++m) {
            int grow = bm + wm + m * 16 + cr;
#pragma unroll
            for (int j = 0; j < 4; ++j) {
                float* cp = C + (size_t)(grow + j) * NDIM + bn + wn + lr;
#pragma unroll
                for (int n = 0; n < 4; ++n)
                    cp[n * 16] = acc[m][n][j];
            }
        }
    } else {
        for (int m = 0; m < 4; ++m) {
            int grow = bm + wm + m * 16 + cr;
            for (int j = 0; j < 4; ++j) {
                long long base = (long long)(grow + j) * NDIM + bn + wn + lr;
                for (int n = 0; n < 4; ++n)
                    if (base + n * 16 < out_elems) C[base + n * 16] = acc[m][n][j];
            }
        }
    }
}

// ---- fp32 fallback (only if ws too small) ----
__global__ void dft_naive(const float* __restrict__ x, const float* __restrict__ wsin,
                          const float* __restrict__ wcos, float* __restrict__ out,
                          long long out_elems, int real_only) {
    __shared__ float xs[K_DIM];
    int row = blockIdx.x;
    const float* xr = x + (size_t)row * K_DIM;
    for (int i = threadIdx.x; i < K_DIM; i += blockDim.x) xs[i] = xr[i];
    __syncthreads();
    for (int k = threadIdx.x; k < K_DIM; k += blockDim.x) {
        const float* wc = wcos + (size_t)k * K_DIM;
        float re = 0.f;
        if (real_only) {
            for (int s = 0; s < K_DIM; ++s) re += xs[s] * wc[s];
            long long o = (long long)row * K_DIM + k;
            if (o < out_elems) out[o] = re;
        } else {
            const float* ws = wsin + (size_t)k * K_DIM;
            float im = 0.f;
            for (int s = 0; s < K_DIM; ++s) { re += xs[s] * wc[s]; im += xs[s] * ws[s]; }
            long long o = ((long long)row * K_DIM + k) * 2;
            if (o + 1 < out_elems) { out[o] = re; out[o + 1] = -im; }
        }
    }
}

extern "C" void kernel_launch(void* const* d_in, const int* in_sizes, int n_in,
                              void* d_out, int out_size, void* d_ws, size_t ws_size,
                              hipStream_t stream) {
    const float* x    = (const float*)d_in[0];
    const float* wsin = (const float*)d_in[1];
    const float* wcos = (const float*)d_in[2];
    float* out = (float*)d_out;

    const int real_only = (out_size == M_TOT * 1024);
    const size_t need = (size_t)M_TOT * K_DIM * 2 + (size_t)2048 * K_DIM * 2;

    if (ws_size >= need) {
        uint16_t* xb = (uint16_t*)d_ws;
        uint16_t* Wb = xb + (size_t)M_TOT * K_DIM;
        if (real_only) {
            build_wc_kernel<<<512, 256, 0, stream>>>(wcos, Wb);
            dft_gemm256f<1024><<<(M_TOT / 256) * (1024 / 256), 512, 0, stream>>>(
                x, Wb, out, (long long)out_size);
        } else {
            cvt_x_kernel<<<2048, 256, 0, stream>>>(x, xb);
            build_w_kernel<<<512, 256, 0, stream>>>(wsin, wcos, Wb);
            dft_gemm128<2048><<<128 * 16, 256, 0, stream>>>(xb, Wb, out, (long long)out_size);
        }
    } else {
        dft_naive<<<M_TOT, 256, 0, stream>>>(x, wsin, wcos, out, (long long)out_size,
                                             real_only);
    }
}

// Round 7
// 54.870 us; speedup vs baseline: 1.5935x; 1.0133x over previous
//
#include <hip/hip_runtime.h>
#include <stdint.h>

#define K_DIM 1024
#define M_TOT 16384
#define BM 128
#define BN 128
#define BK 64

typedef __attribute__((ext_vector_type(8))) short bf16x8;
typedef __attribute__((ext_vector_type(4))) float f32x4;
typedef __attribute__((ext_vector_type(8))) unsigned short u16x8;

__device__ inline uint16_t f2bf(float f) {
    union { float f; uint32_t u; } v; v.f = f;
    return (uint16_t)((v.u + 0x7fffu + ((v.u >> 16) & 1u)) >> 16);
}

// ---- x (16M f32) -> bf16 (only used by the 2048 fallback path) ----
__global__ void cvt_x_kernel(const float* __restrict__ x, uint16_t* __restrict__ xb) {
    const size_t n8 = (size_t)M_TOT * K_DIM / 8;
    for (size_t i = (size_t)blockIdx.x * blockDim.x + threadIdx.x; i < n8;
         i += (size_t)gridDim.x * blockDim.x) {
        const float4* s = (const float4*)x + i * 2;
        float4 a = s[0], b = s[1];
        u16x8 v;
        v[0] = f2bf(a.x); v[1] = f2bf(a.y); v[2] = f2bf(a.z); v[3] = f2bf(a.w);
        v[4] = f2bf(b.x); v[5] = f2bf(b.y); v[6] = f2bf(b.z); v[7] = f2bf(b.w);
        *(u16x8*)(xb + i * 8) = v;
    }
}

// ---- real-only weights: Wc[k][s] = cos(2*pi*k*s/N), bf16 [1024][1024] ----
__global__ void build_wc_kernel(const float* __restrict__ wcos, uint16_t* __restrict__ W) {
    int i = blockIdx.x * blockDim.x + threadIdx.x;
    int k = i >> 7;
    int sc = (i & 127) * 8;
    const float4* c = (const float4*)(wcos + (size_t)k * K_DIM + sc);
    float4 c0 = c[0], c1 = c[1];
    u16x8 vc;
    vc[0] = f2bf(c0.x); vc[1] = f2bf(c0.y); vc[2] = f2bf(c0.z); vc[3] = f2bf(c0.w);
    vc[4] = f2bf(c1.x); vc[5] = f2bf(c1.y); vc[6] = f2bf(c1.z); vc[7] = f2bf(c1.w);
    *(u16x8*)(W + (size_t)k * K_DIM + sc) = vc;
}

// ---- interleaved weights (fallback path): W[2k][s]=cos, W[2k+1][s]=-sin ----
__global__ void build_w_kernel(const float* __restrict__ wsin, const float* __restrict__ wcos,
                               uint16_t* __restrict__ W) {
    int i = blockIdx.x * blockDim.x + threadIdx.x;
    int k = i >> 7;
    int sc = (i & 127) * 8;
    const float4* c = (const float4*)(wcos + (size_t)k * K_DIM + sc);
    const float4* s = (const float4*)(wsin + (size_t)k * K_DIM + sc);
    float4 c0 = c[0], c1 = c[1], s0 = s[0], s1 = s[1];
    u16x8 vc, vs;
    vc[0] = f2bf(c0.x); vc[1] = f2bf(c0.y); vc[2] = f2bf(c0.z); vc[3] = f2bf(c0.w);
    vc[4] = f2bf(c1.x); vc[5] = f2bf(c1.y); vc[6] = f2bf(c1.z); vc[7] = f2bf(c1.w);
    vs[0] = f2bf(-s0.x); vs[1] = f2bf(-s0.y); vs[2] = f2bf(-s0.z); vs[3] = f2bf(-s0.w);
    vs[4] = f2bf(-s1.x); vs[5] = f2bf(-s1.y); vs[6] = f2bf(-s1.z); vs[7] = f2bf(-s1.w);
    *(u16x8*)(W + (size_t)(2 * k) * K_DIM + sc) = vc;
    *(u16x8*)(W + (size_t)(2 * k + 1) * K_DIM + sc) = vs;
}

// =====================================================================
// Fused-cvt 256x256 bf16 MFMA GEMM:  C[M][NDIM] = cvt(X[M][K]) * B[NDIM][K]^T
//   A: reg-staged f32 loads issued at tile top for t+1; cvt+ds_write moved
//      into the tile body (overlapped with kk=32 phases), NOT the end tail.
//   B: global_load_lds, pre-swizzled source, linear LDS dest (T2 rule 21).
//   Double-buffered 128 KiB LDS; raw barriers; minimal end-of-tile drain.
// =====================================================================
template <int NDIM>
__global__ __launch_bounds__(512, 2) void dft_gemm256f(const float* __restrict__ X,
                                                       const uint16_t* __restrict__ Bw,
                                                       float* __restrict__ C,
                                                       long long out_elems) {
    constexpr int BM2 = 256, BN2 = 256, BK2 = 64;
    constexpr int NT = NDIM / BN2;
    constexpr int NKT = K_DIM / BK2;
    __shared__ uint16_t lds[2][2][BM2 * BK2];   // [dbuf][A=0/B=1][256*64]

    const int t = threadIdx.x;
    const int l = t & 63;
    const int wid = t >> 6;
    const int wr = wid >> 2;      // M half
    const int wc = wid & 3;       // N quarter
    const int lr = l & 15;
    const int lhi = l >> 4;
    const int xr7 = lr & 7;

    // T1: bijective XCD swizzle (grid % 8 == 0)
    int bid = blockIdx.x;
    {
        int nwg = gridDim.x;
        if ((nwg & 7) == 0) { int q = nwg >> 3; bid = (bid & 7) * q + (bid >> 3); }
    }
    const int bm = (bid / NT) * BM2;
    const int bn = (bid % NT) * BN2;

    // thread t handles rows r0 + i*64, slot sl (8 elems = 16 B)
    const int r0 = t >> 3, sl = t & 7;
    const float* gA0 = X + (size_t)(bm + r0) * K_DIM + sl * 8;                  // linear src
    const int wA0 = (r0 * 8 + (sl ^ (r0 & 7))) * 16;                            // swz LDS byte
    const uint16_t* gB0 = Bw + (size_t)(bn + r0) * K_DIM + (sl ^ (r0 & 7)) * 8; // pre-swz src
    const int ldsB0 = (t & ~63) * 16;                                           // wave-uniform

    float4 ra[4][2];

    auto loadA = [&](int kt) {
        const int k0 = kt * BK2;
#pragma unroll
        for (int i = 0; i < 4; ++i) {
            const float* p = gA0 + (size_t)i * 64 * K_DIM + k0;
            ra[i][0] = *(const float4*)p;
            ra[i][1] = *(const float4*)(p + 4);
        }
    };
    auto stageB = [&](int d, int kt) {
        const int k0 = kt * BK2;
#pragma unroll
        for (int i = 0; i < 4; ++i)
            __builtin_amdgcn_global_load_lds(
                (const __attribute__((address_space(1))) void*)(gB0 + (size_t)i * 64 * K_DIM + k0),
                (__attribute__((address_space(3))) void*)((char*)&lds[d][1][0] + ldsB0 + i * 8192),
                16, 0, 0);
    };
    auto writeA = [&](int d) {
#pragma unroll
        for (int i = 0; i < 4; ++i) {
            union { u16x8 v; uint32_t w[4]; } u;
            asm("v_cvt_pk_bf16_f32 %0, %1, %2" : "=v"(u.w[0]) : "v"(ra[i][0].x), "v"(ra[i][0].y));
            asm("v_cvt_pk_bf16_f32 %0, %1, %2" : "=v"(u.w[1]) : "v"(ra[i][0].z), "v"(ra[i][0].w));
            asm("v_cvt_pk_bf16_f32 %0, %1, %2" : "=v"(u.w[2]) : "v"(ra[i][1].x), "v"(ra[i][1].y));
            asm("v_cvt_pk_bf16_f32 %0, %1, %2" : "=v"(u.w[3]) : "v"(ra[i][1].z), "v"(ra[i][1].w));
            *(u16x8*)((char*)&lds[d][0][0] + wA0 + i * 8192) = u.v;
        }
    };
    // swizzled fragment read: element = row*64 + ((slot ^ (row&7))*8)
    auto loadFrag = [&](const uint16_t* base, int row, int kk) -> bf16x8 {
        int s = (kk >> 3) + lhi;
        return *(const bf16x8*)(base + row * 64 + ((s ^ xr7) * 8));
    };

    f32x4 acc[8][4] = {};

    // ---- prologue: tile 0 ----
    loadA(0);
    stageB(0, 0);
    __builtin_amdgcn_sched_barrier(0);
    asm volatile("s_waitcnt vmcnt(0)" ::: "memory");
    __builtin_amdgcn_sched_barrier(0);
    writeA(0);
    asm volatile("s_waitcnt lgkmcnt(0)" ::: "memory");
    __builtin_amdgcn_s_barrier();
    __builtin_amdgcn_sched_barrier(0);

    // ---- main loop ----
    for (int kt = 0; kt < NKT; ++kt) {
        const int c = kt & 1;
        const uint16_t* bA = &lds[c][0][0];
        const uint16_t* bB = &lds[c][1][0];
        const bool more = (kt + 1 < NKT);
        if (more) { loadA(kt + 1); stageB(1 - c, kt + 1); }   // issue-early (T14)
        __builtin_amdgcn_sched_barrier(0);

        // ======== kk = 0 ========
        {
            bf16x8 bfrag[4];
#pragma unroll
            for (int n = 0; n < 4; ++n) bfrag[n] = loadFrag(bB, wc * 64 + n * 16 + lr, 0);
            bf16x8 afr[4];
#pragma unroll
            for (int mm = 0; mm < 4; ++mm)
                afr[mm] = loadFrag(bA, wr * 128 + mm * 16 + lr, 0);
            __builtin_amdgcn_s_setprio(1);
#pragma unroll
            for (int mm = 0; mm < 4; ++mm)
#pragma unroll
                for (int nn = 0; nn < 4; ++nn)
                    acc[mm][nn] = __builtin_amdgcn_mfma_f32_16x16x32_bf16(
                        afr[mm], bfrag[nn], acc[mm][nn], 0, 0, 0);
            __builtin_amdgcn_s_setprio(0);
            __builtin_amdgcn_s_barrier();
#pragma unroll
            for (int mm = 0; mm < 4; ++mm)
                afr[mm] = loadFrag(bA, wr * 128 + 64 + mm * 16 + lr, 0);
            __builtin_amdgcn_s_setprio(1);
#pragma unroll
            for (int mm = 0; mm < 4; ++mm)
#pragma unroll
                for (int nn = 0; nn < 4; ++nn)
                    acc[4 + mm][nn] = __builtin_amdgcn_mfma_f32_16x16x32_bf16(
                        afr[mm], bfrag[nn], acc[4 + mm][nn], 0, 0, 0);
            __builtin_amdgcn_s_setprio(0);
            __builtin_amdgcn_s_barrier();
        }

        // ======== kk = 32 ========
        {
            bf16x8 bfrag[4];
#pragma unroll
            for (int n = 0; n < 4; ++n) bfrag[n] = loadFrag(bB, wc * 64 + n * 16 + lr, 32);
            bf16x8 afr[4];
#pragma unroll
            for (int mm = 0; mm < 4; ++mm)
                afr[mm] = loadFrag(bA, wr * 128 + mm * 16 + lr, 32);
            __builtin_amdgcn_s_setprio(1);
#pragma unroll
            for (int mm = 0; mm < 4; ++mm)
#pragma unroll
                for (int nn = 0; nn < 4; ++nn)
                    acc[mm][nn] = __builtin_amdgcn_mfma_f32_16x16x32_bf16(
                        afr[mm], bfrag[nn], acc[mm][nn], 0, 0, 0);
            __builtin_amdgcn_s_setprio(0);
            __builtin_amdgcn_s_barrier();

            // ---- overlapped A cvt+write for tile kt+1 (buf[1-c] is dead:
            //      its readers passed the end-of-(kt-1) barrier; every wave
            //      passed the m0 barrier above). Compiler auto-inserts the
            //      counted vmcnt before the cvt's ra uses. ----
            if (more) {
                __builtin_amdgcn_sched_barrier(0);
                writeA(1 - c);
                __builtin_amdgcn_sched_barrier(0);
            }

#pragma unroll
            for (int mm = 0; mm < 4; ++mm)
                afr[mm] = loadFrag(bA, wr * 128 + 64 + mm * 16 + lr, 32);
            __builtin_amdgcn_s_setprio(1);
#pragma unroll
            for (int mm = 0; mm < 4; ++mm)
#pragma unroll
                for (int nn = 0; nn < 4; ++nn)
                    acc[4 + mm][nn] = __builtin_amdgcn_mfma_f32_16x16x32_bf16(
                        afr[mm], bfrag[nn], acc[4 + mm][nn], 0, 0, 0);
            __builtin_amdgcn_s_setprio(0);
        }

        // ---- end of tile: B-DMA (issued a full tile ago) + A ds_writes
        //      must be visible before next tile's reads. ----
        __builtin_amdgcn_sched_barrier(0);
        asm volatile("s_waitcnt vmcnt(0)" ::: "memory");
        asm volatile("s_waitcnt lgkmcnt(0)" ::: "memory");
        __builtin_amdgcn_s_barrier();
        __builtin_amdgcn_sched_barrier(0);
    }

    // ---- epilogue: C/D layout (m89): col = lane&15, row = (lane>>4)*4 + j ----
    const int cr = lhi * 4;
    const bool safe = ((long long)(bm + BM2) * NDIM) <= out_elems;
    if (safe) {
#pragma unroll
        for (int m = 0; m < 8; ++m) {
            int grow = bm + wr * 128 + m * 16 + cr;
#pragma unroll
            for (int j = 0; j < 4; ++j) {
                float* cp = C + (size_t)(grow + j) * NDIM + bn + wc * 64 + lr;
#pragma unroll
                for (int n = 0; n < 4; ++n)
                    cp[n * 16] = acc[m][n][j];
            }
        }
    } else {
        for (int m = 0; m < 8; ++m) {
            int grow = bm + wr * 128 + m * 16 + cr;
            for (int j = 0; j < 4; ++j) {
                long long base = (long long)(grow + j) * NDIM + bn + wc * 64 + lr;
                for (int n = 0; n < 4; ++n)
                    if (base + n * 16 < out_elems) C[base + n * 16] = acc[m][n][j];
            }
        }
    }
}

// ---- 128x128 gload_lds GEMM (fallback for the interleaved/2048 path) ----
template <int NDIM>
__global__ __launch_bounds__(256) void dft_gemm128(const uint16_t* __restrict__ A,
                                                   const uint16_t* __restrict__ B,
                                                   float* __restrict__ C,
                                                   long long out_elems) {
    constexpr int NT = NDIM / BN;
    __shared__ uint16_t As[BM * BK];
    __shared__ uint16_t Bs[BN * BK];

    const int t = threadIdx.x;
    const int l = t & 63;
    const int w = t >> 6;

    int bid = blockIdx.x;
    {
        int nwg = gridDim.x;
        if ((nwg & 7) == 0) { int q = nwg >> 3; bid = (bid & 7) * q + (bid >> 3); }
    }
    const int bm = (bid / NT) * BM;
    const int bn = (bid % NT) * BN;

    const uint16_t* gA[4];
    const uint16_t* gB[4];
    int ldsOff[4];
#pragma unroll
    for (int i = 0; i < 4; ++i) {
        int chunk = i * 256 + t;
        int row = chunk >> 3;
        int cc = (chunk & 7) * 8;
        gA[i] = A + (size_t)(bm + row) * K_DIM + cc;
        gB[i] = B + (size_t)(bn + row) * K_DIM + cc;
        ldsOff[i] = (i * 256 + (t & 192)) * 16;
    }

    const int wm = ((w >> 1) & 1) * 64;
    const int wn = (w & 1) * 64;
    const int lr = l & 15;
    const int lk = (l >> 4) * 8;

    f32x4 acc[4][4] = {};

    for (int k0 = 0; k0 < K_DIM; k0 += BK) {
#pragma unroll
        for (int i = 0; i < 4; ++i)
            __builtin_amdgcn_global_load_lds(
                (const __attribute__((address_space(1))) void*)(gA[i] + k0),
                (__attribute__((address_space(3))) void*)((char*)As + ldsOff[i]), 16, 0, 0);
#pragma unroll
        for (int i = 0; i < 4; ++i)
            __builtin_amdgcn_global_load_lds(
                (const __attribute__((address_space(1))) void*)(gB[i] + k0),
                (__attribute__((address_space(3))) void*)((char*)Bs + ldsOff[i]), 16, 0, 0);
        __syncthreads();
#pragma unroll
        for (int kk = 0; kk < BK; kk += 32) {
            bf16x8 af[4], bfr[4];
#pragma unroll
            for (int m = 0; m < 4; ++m)
                af[m] = *(const bf16x8*)&As[(wm + m * 16 + lr) * BK + kk + lk];
#pragma unroll
            for (int n = 0; n < 4; ++n)
                bfr[n] = *(const bf16x8*)&Bs[(wn + n * 16 + lr) * BK + kk + lk];
#pragma unroll
            for (int m = 0; m < 4; ++m)
#pragma unroll
                for (int n = 0; n < 4; ++n)
                    acc[m][n] = __builtin_amdgcn_mfma_f32_16x16x32_bf16(af[m], bfr[n],
                                                                        acc[m][n], 0, 0, 0);
        }
        __syncthreads();
    }

    const int cr = (l >> 4) * 4;
    const bool safe = ((long long)(bm + BM) * NDIM) <= out_elems;
    if (safe) {
#pragma unroll
        for (int m = 0; m < 4; ++m) {
            int grow = bm + wm + m * 16 + cr;
#pragma unroll
            for (int j = 0; j < 4; ++j) {
                float* cp = C + (size_t)(grow + j) * NDIM + bn + wn + lr;
#pragma unroll
                for (int n = 0; n < 4; ++n)
                    cp[n * 16] = acc[m][n][j];
            }
        }
    } else {
        for (int m = 0; m < 4; ++m) {
            int grow = bm + wm + m * 16 + cr;
            for (int j = 0; j < 4; ++j) {
                long long base = (long long)(grow + j) * NDIM + bn + wn + lr;
                for (int n = 0; n < 4; ++n)
                    if (base + n * 16 < out_elems) C[base + n * 16] = acc[m][n][j];
            }
        }
    }
}

// ---- fp32 fallback (only if ws too small) ----
__global__ void dft_naive(const float* __restrict__ x, const float* __restrict__ wsin,
                          const float* __restrict__ wcos, float* __restrict__ out,
                          long long out_elems, int real_only) {
    __shared__ float xs[K_DIM];
    int row = blockIdx.x;
    const float* xr = x + (size_t)row * K_DIM;
    for (int i = threadIdx.x; i < K_DIM; i += blockDim.x) xs[i] = xr[i];
    __syncthreads();
    for (int k = threadIdx.x; k < K_DIM; k += blockDim.x) {
        const float* wc = wcos + (size_t)k * K_DIM;
        float re = 0.f;
        if (real_only) {
            for (int s = 0; s < K_DIM; ++s) re += xs[s] * wc[s];
            long long o = (long long)row * K_DIM + k;
            if (o < out_elems) out[o] = re;
        } else {
            const float* ws = wsin + (size_t)k * K_DIM;
            float im = 0.f;
            for (int s = 0; s < K_DIM; ++s) { re += xs[s] * wc[s]; im += xs[s] * ws[s]; }
            long long o = ((long long)row * K_DIM + k) * 2;
            if (o + 1 < out_elems) { out[o] = re; out[o + 1] = -im; }
        }
    }
}

extern "C" void kernel_launch(void* const* d_in, const int* in_sizes, int n_in,
                              void* d_out, int out_size, void* d_ws, size_t ws_size,
                              hipStream_t stream) {
    const float* x    = (const float*)d_in[0];
    const float* wsin = (const float*)d_in[1];
    const float* wcos = (const float*)d_in[2];
    float* out = (float*)d_out;

    const int real_only = (out_size == M_TOT * 1024);
    const size_t need = (size_t)M_TOT * K_DIM * 2 + (size_t)2048 * K_DIM * 2;

    if (ws_size >= need) {
        uint16_t* xb = (uint16_t*)d_ws;
        uint16_t* Wb = xb + (size_t)M_TOT * K_DIM;
        if (real_only) {
            build_wc_kernel<<<512, 256, 0, stream>>>(wcos, Wb);
            dft_gemm256f<1024><<<(M_TOT / 256) * (1024 / 256), 512, 0, stream>>>(
                x, Wb, out, (long long)out_size);
        } else {
            cvt_x_kernel<<<2048, 256, 0, stream>>>(x, xb);
            build_w_kernel<<<512, 256, 0, stream>>>(wsin, wcos, Wb);
            dft_gemm128<2048><<<128 * 16, 256, 0, stream>>>(xb, Wb, out, (long long)out_size);
        }
    } else {
        dft_naive<<<M_TOT, 256, 0, stream>>>(x, wsin, wcos, out, (long long)out_size,
                                             real_only);
    }
}

// Round 8
// 52.706 us; speedup vs baseline: 1.6589x; 1.0410x over previous
//
#include <hip/hip_runtime.h>
#include <stdint.h>

#define K_DIM 1024
#define M_TOT 16384
#define BM 128
#define BN 128
#define BK 64

typedef __attribute__((ext_vector_type(8))) short bf16x8;
typedef __attribute__((ext_vector_type(4))) float f32x4;
typedef __attribute__((ext_vector_type(8))) unsigned short u16x8;

__device__ inline uint16_t f2bf(float f) {
    union { float f; uint32_t u; } v; v.f = f;
    return (uint16_t)((v.u + 0x7fffu + ((v.u >> 16) & 1u)) >> 16);
}

// ---- x (16M f32) -> bf16 (only used by the 2048 fallback path) ----
__global__ void cvt_x_kernel(const float* __restrict__ x, uint16_t* __restrict__ xb) {
    const size_t n8 = (size_t)M_TOT * K_DIM / 8;
    for (size_t i = (size_t)blockIdx.x * blockDim.x + threadIdx.x; i < n8;
         i += (size_t)gridDim.x * blockDim.x) {
        const float4* s = (const float4*)x + i * 2;
        float4 a = s[0], b = s[1];
        u16x8 v;
        v[0] = f2bf(a.x); v[1] = f2bf(a.y); v[2] = f2bf(a.z); v[3] = f2bf(a.w);
        v[4] = f2bf(b.x); v[5] = f2bf(b.y); v[6] = f2bf(b.z); v[7] = f2bf(b.w);
        *(u16x8*)(xb + i * 8) = v;
    }
}

// ---- real-only weights: Wc[k][s] = cos(2*pi*k*s/N), bf16 [1024][1024] ----
__global__ void build_wc_kernel(const float* __restrict__ wcos, uint16_t* __restrict__ W) {
    int i = blockIdx.x * blockDim.x + threadIdx.x;
    int k = i >> 7;
    int sc = (i & 127) * 8;
    const float4* c = (const float4*)(wcos + (size_t)k * K_DIM + sc);
    float4 c0 = c[0], c1 = c[1];
    u16x8 vc;
    vc[0] = f2bf(c0.x); vc[1] = f2bf(c0.y); vc[2] = f2bf(c0.z); vc[3] = f2bf(c0.w);
    vc[4] = f2bf(c1.x); vc[5] = f2bf(c1.y); vc[6] = f2bf(c1.z); vc[7] = f2bf(c1.w);
    *(u16x8*)(W + (size_t)k * K_DIM + sc) = vc;
}

// ---- interleaved weights (fallback path): W[2k][s]=cos, W[2k+1][s]=-sin ----
__global__ void build_w_kernel(const float* __restrict__ wsin, const float* __restrict__ wcos,
                               uint16_t* __restrict__ W) {
    int i = blockIdx.x * blockDim.x + threadIdx.x;
    int k = i >> 7;
    int sc = (i & 127) * 8;
    const float4* c = (const float4*)(wcos + (size_t)k * K_DIM + sc);
    const float4* s = (const float4*)(wsin + (size_t)k * K_DIM + sc);
    float4 c0 = c[0], c1 = c[1], s0 = s[0], s1 = s[1];
    u16x8 vc, vs;
    vc[0] = f2bf(c0.x); vc[1] = f2bf(c0.y); vc[2] = f2bf(c0.z); vc[3] = f2bf(c0.w);
    vc[4] = f2bf(c1.x); vc[5] = f2bf(c1.y); vc[6] = f2bf(c1.z); vc[7] = f2bf(c1.w);
    vs[0] = f2bf(-s0.x); vs[1] = f2bf(-s0.y); vs[2] = f2bf(-s0.z); vs[3] = f2bf(-s0.w);
    vs[4] = f2bf(-s1.x); vs[5] = f2bf(-s1.y); vs[6] = f2bf(-s1.z); vs[7] = f2bf(-s1.w);
    *(u16x8*)(W + (size_t)(2 * k) * K_DIM + sc) = vc;
    *(u16x8*)(W + (size_t)(2 * k + 1) * K_DIM + sc) = vs;
}

// =====================================================================
// Fused-cvt 256x256 bf16 MFMA GEMM, per-phase staggered schedule (T3+T4):
//   4 phases/K-tile, each {ds_reads ∥ one stage slice -> BAR -> 16 MFMA -> BAR}
//   p0: issue B-DMA(kt+1);  p2/p3: vmcnt(8) -> cvt+writeA half -> issue
//   A-reg loads for kt+2 (4-phase issue->use distance covers HBM latency).
//   p3-end: vmcnt(8)+lgkmcnt(0) (waits only B(kt+1); A loads stay in flight
//   across barriers — never vmcnt(0) in the main loop).  Staging wraps mod
//   NKT so all vmcnt literals are uniform.
// =====================================================================
template <int NDIM>
__global__ __launch_bounds__(512, 2) void dft_gemm256f(const float* __restrict__ X,
                                                       const uint16_t* __restrict__ Bw,
                                                       float* __restrict__ C,
                                                       long long out_elems) {
    constexpr int BM2 = 256, BN2 = 256, BK2 = 64;
    constexpr int NT = NDIM / BN2;
    constexpr int NKT = K_DIM / BK2;
    __shared__ uint16_t lds[2][2][BM2 * BK2];   // [dbuf][A=0/B=1][256*64]

    const int t = threadIdx.x;
    const int l = t & 63;
    const int wid = t >> 6;
    const int wr = wid >> 2;      // M half
    const int wc = wid & 3;       // N quarter
    const int lr = l & 15;
    const int lhi = l >> 4;
    const int xr7 = lr & 7;

    // T1: bijective XCD swizzle (grid % 8 == 0)
    int bid = blockIdx.x;
    {
        int nwg = gridDim.x;
        if ((nwg & 7) == 0) { int q = nwg >> 3; bid = (bid & 7) * q + (bid >> 3); }
    }
    const int bm = (bid / NT) * BM2;
    const int bn = (bid % NT) * BN2;

    // thread t stages rows r0 + i*64 (i=0..3), slot sl (8 elems = 16 B)
    const int r0 = t >> 3, sl = t & 7;
    const float* gA0 = X + (size_t)(bm + r0) * K_DIM + sl * 8;                  // linear src
    const int wA0 = (r0 * 8 + (sl ^ (r0 & 7))) * 16;                            // swz LDS byte
    const uint16_t* gB0 = Bw + (size_t)(bn + r0) * K_DIM + (sl ^ (r0 & 7)) * 8; // pre-swz src
    const int ldsB0 = (t & ~63) * 16;                                           // wave-uniform

    float4 ra[4][2];   // in-flight A f32: i<2 = half0 (rows r0, r0+64), i>=2 = half1

    auto loadA_half = [&](int kt, int h) {
        const int k0 = kt * BK2;
#pragma unroll
        for (int i = 2 * h; i < 2 * h + 2; ++i) {
            const float* p = gA0 + (size_t)i * 64 * K_DIM + k0;
            ra[i][0] = *(const float4*)p;
            ra[i][1] = *(const float4*)(p + 4);
        }
    };
    auto stageB_all = [&](int d, int kt) {
        const int k0 = kt * BK2;
#pragma unroll
        for (int i = 0; i < 4; ++i)
            __builtin_amdgcn_global_load_lds(
                (const __attribute__((address_space(1))) void*)(gB0 + (size_t)i * 64 * K_DIM + k0),
                (__attribute__((address_space(3))) void*)((char*)&lds[d][1][0] + ldsB0 + i * 8192),
                16, 0, 0);
    };
    auto writeA_half = [&](int d, int h) {
#pragma unroll
        for (int i = 2 * h; i < 2 * h + 2; ++i) {
            union { u16x8 v; uint32_t w[4]; } u;
            asm("v_cvt_pk_bf16_f32 %0, %1, %2" : "=v"(u.w[0]) : "v"(ra[i][0].x), "v"(ra[i][0].y));
            asm("v_cvt_pk_bf16_f32 %0, %1, %2" : "=v"(u.w[1]) : "v"(ra[i][0].z), "v"(ra[i][0].w));
            asm("v_cvt_pk_bf16_f32 %0, %1, %2" : "=v"(u.w[2]) : "v"(ra[i][1].x), "v"(ra[i][1].y));
            asm("v_cvt_pk_bf16_f32 %0, %1, %2" : "=v"(u.w[3]) : "v"(ra[i][1].z), "v"(ra[i][1].w));
            *(u16x8*)((char*)&lds[d][0][0] + wA0 + i * 8192) = u.v;
        }
    };
    // swizzled fragment read: element = row*64 + ((slot ^ (row&7))*8)
    auto loadFrag = [&](const uint16_t* base, int row, int kk) -> bf16x8 {
        int s = (kk >> 3) + lhi;
        return *(const bf16x8*)(base + row * 64 + ((s ^ xr7) * 8));
    };

    f32x4 acc[8][4] = {};

    // ---- prologue: tile 0 staged; A-regs for tile 1 in flight ----
    loadA_half(0, 0); loadA_half(0, 1);     // 8 VMEM (oldest)
    stageB_all(0, 0);                        // 4 VMEM
    __builtin_amdgcn_sched_barrier(0);
    asm volatile("s_waitcnt vmcnt(4)" ::: "memory");   // A(0) regs landed; B(0) in flight
    __builtin_amdgcn_sched_barrier(0);
    writeA_half(0, 0); writeA_half(0, 1);
    loadA_half(1, 0); loadA_half(1, 1);      // A for tile 1 (consumed at kt=0 p2/p3)
    __builtin_amdgcn_sched_barrier(0);
    asm volatile("s_waitcnt vmcnt(8) lgkmcnt(0)" ::: "memory");  // B(0) landed; A(1) x8 in flight
    __builtin_amdgcn_s_barrier();
    __builtin_amdgcn_sched_barrier(0);

    // ---- main loop: steady queue at p2 = [Ah0(kt+1)4, Ah1(kt+1)4, B(kt+1)4] ----
    for (int kt = 0; kt < NKT; ++kt) {
        const int cc = kt & 1;
        const uint16_t* bA = &lds[cc][0][0];
        const uint16_t* bB = &lds[cc][1][0];
        int ktn = kt + 1;  if (ktn >= NKT) ktn -= NKT;    // wrap: uniform counts
        int ktnn = kt + 2; if (ktnn >= NKT) ktnn -= NKT;

        bf16x8 bfr[4], af[4];

        // ======== p0: ks=0, m-half 0  (+ issue B-DMA for kt+1) ========
#pragma unroll
        for (int n = 0; n < 4; ++n) bfr[n] = loadFrag(bB, wc * 64 + n * 16 + lr, 0);
#pragma unroll
        for (int m = 0; m < 4; ++m) af[m] = loadFrag(bA, wr * 128 + m * 16 + lr, 0);
        stageB_all(1 - cc, ktn);
        __builtin_amdgcn_sched_barrier(0);
        __builtin_amdgcn_s_barrier();
        __builtin_amdgcn_s_setprio(1);
#pragma unroll
        for (int m = 0; m < 4; ++m)
#pragma unroll
            for (int n = 0; n < 4; ++n)
                acc[m][n] = __builtin_amdgcn_mfma_f32_16x16x32_bf16(af[m], bfr[n], acc[m][n], 0, 0, 0);
        __builtin_amdgcn_s_setprio(0);
        __builtin_amdgcn_s_barrier();

        // ======== p1: ks=0, m-half 1 ========
#pragma unroll
        for (int m = 0; m < 4; ++m) af[m] = loadFrag(bA, wr * 128 + 64 + m * 16 + lr, 0);
        __builtin_amdgcn_sched_barrier(0);
        __builtin_amdgcn_s_barrier();
        __builtin_amdgcn_s_setprio(1);
#pragma unroll
        for (int m = 0; m < 4; ++m)
#pragma unroll
            for (int n = 0; n < 4; ++n)
                acc[4 + m][n] = __builtin_amdgcn_mfma_f32_16x16x32_bf16(af[m], bfr[n], acc[4 + m][n], 0, 0, 0);
        __builtin_amdgcn_s_setprio(0);
        __builtin_amdgcn_s_barrier();

        // ======== p2: ks=1, m-half 0  (+ writeA half0, issue A(kt+2) half0) ========
#pragma unroll
        for (int n = 0; n < 4; ++n) bfr[n] = loadFrag(bB, wc * 64 + n * 16 + lr, 32);
#pragma unroll
        for (int m = 0; m < 4; ++m) af[m] = loadFrag(bA, wr * 128 + m * 16 + lr, 32);
        asm volatile("s_waitcnt vmcnt(8)" ::: "memory");   // Ah0(kt+1) landed
        __builtin_amdgcn_sched_barrier(0);
        writeA_half(1 - cc, 0);
        loadA_half(ktnn, 0);
        __builtin_amdgcn_sched_barrier(0);
        __builtin_amdgcn_s_barrier();
        __builtin_amdgcn_s_setprio(1);
#pragma unroll
        for (int m = 0; m < 4; ++m)
#pragma unroll
            for (int n = 0; n < 4; ++n)
                acc[m][n] = __builtin_amdgcn_mfma_f32_16x16x32_bf16(af[m], bfr[n], acc[m][n], 0, 0, 0);
        __builtin_amdgcn_s_setprio(0);
        __builtin_amdgcn_s_barrier();

        // ======== p3: ks=1, m-half 1  (+ writeA half1, issue A(kt+2) half1) ========
#pragma unroll
        for (int m = 0; m < 4; ++m) af[m] = loadFrag(bA, wr * 128 + 64 + m * 16 + lr, 32);
        asm volatile("s_waitcnt vmcnt(8)" ::: "memory");   // Ah1(kt+1) landed
        __builtin_amdgcn_sched_barrier(0);
        writeA_half(1 - cc, 1);
        loadA_half(ktnn, 1);
        __builtin_amdgcn_sched_barrier(0);
        __builtin_amdgcn_s_barrier();
        __builtin_amdgcn_s_setprio(1);
#pragma unroll
        for (int m = 0; m < 4; ++m)
#pragma unroll
            for (int n = 0; n < 4; ++n)
                acc[4 + m][n] = __builtin_amdgcn_mfma_f32_16x16x32_bf16(af[m], bfr[n], acc[4 + m][n], 0, 0, 0);
        __builtin_amdgcn_s_setprio(0);
        // end of tile: B(kt+1) (oldest 4) landed; A(kt+2) x8 stay in flight.
        asm volatile("s_waitcnt vmcnt(8) lgkmcnt(0)" ::: "memory");
        __builtin_amdgcn_sched_barrier(0);
        __builtin_amdgcn_s_barrier();
        __builtin_amdgcn_sched_barrier(0);
    }

    // ---- epilogue: C/D layout (m89): col = lane&15, row = (lane>>4)*4 + j ----
    const int cr = lhi * 4;
    const bool safe = ((long long)(bm + BM2) * NDIM) <= out_elems;
    if (safe) {
#pragma unroll
        for (int m = 0; m < 8; ++m) {
            int grow = bm + wr * 128 + m * 16 + cr;
#pragma unroll
            for (int j = 0; j < 4; ++j) {
                float* cp = C + (size_t)(grow + j) * NDIM + bn + wc * 64 + lr;
#pragma unroll
                for (int n = 0; n < 4; ++n)
                    cp[n * 16] = acc[m][n][j];
            }
        }
    } else {
        for (int m = 0; m < 8; ++m) {
            int grow = bm + wr * 128 + m * 16 + cr;
            for (int j = 0; j < 4; ++j) {
                long long base = (long long)(grow + j) * NDIM + bn + wc * 64 + lr;
                for (int n = 0; n < 4; ++n)
                    if (base + n * 16 < out_elems) C[base + n * 16] = acc[m][n][j];
            }
        }
    }
}

// ---- 128x128 gload_lds GEMM (fallback for the interleaved/2048 path) ----
template <int NDIM>
__global__ __launch_bounds__(256) void dft_gemm128(const uint16_t* __restrict__ A,
                                                   const uint16_t* __restrict__ B,
                                                   float* __restrict__ C,
                                                   long long out_elems) {
    constexpr int NT = NDIM / BN;
    __shared__ uint16_t As[BM * BK];
    __shared__ uint16_t Bs[BN * BK];

    const int t = threadIdx.x;
    const int l = t & 63;
    const int w = t >> 6;

    int bid = blockIdx.x;
    {
        int nwg = gridDim.x;
        if ((nwg & 7) == 0) { int q = nwg >> 3; bid = (bid & 7) * q + (bid >> 3); }
    }
    const int bm = (bid / NT) * BM;
    const int bn = (bid % NT) * BN;

    const uint16_t* gA[4];
    const uint16_t* gB[4];
    int ldsOff[4];
#pragma unroll
    for (int i = 0; i < 4; ++i) {
        int chunk = i * 256 + t;
        int row = chunk >> 3;
        int cc = (chunk & 7) * 8;
        gA[i] = A + (size_t)(bm + row) * K_DIM + cc;
        gB[i] = B + (size_t)(bn + row) * K_DIM + cc;
        ldsOff[i] = (i * 256 + (t & 192)) * 16;
    }

    const int wm = ((w >> 1) & 1) * 64;
    const int wn = (w & 1) * 64;
    const int lr = l & 15;
    const int lk = (l >> 4) * 8;

    f32x4 acc[4][4] = {};

    for (int k0 = 0; k0 < K_DIM; k0 += BK) {
#pragma unroll
        for (int i = 0; i < 4; ++i)
            __builtin_amdgcn_global_load_lds(
                (const __attribute__((address_space(1))) void*)(gA[i] + k0),
                (__attribute__((address_space(3))) void*)((char*)As + ldsOff[i]), 16, 0, 0);
#pragma unroll
        for (int i = 0; i < 4; ++i)
            __builtin_amdgcn_global_load_lds(
                (const __attribute__((address_space(1))) void*)(gB[i] + k0),
                (__attribute__((address_space(3))) void*)((char*)Bs + ldsOff[i]), 16, 0, 0);
        __syncthreads();
#pragma unroll
        for (int kk = 0; kk < BK; kk += 32) {
            bf16x8 af[4], bfr[4];
#pragma unroll
            for (int m = 0; m < 4; ++m)
                af[m] = *(const bf16x8*)&As[(wm + m * 16 + lr) * BK + kk + lk];
#pragma unroll
            for (int n = 0; n < 4; ++n)
                bfr[n] = *(const bf16x8*)&Bs[(wn + n * 16 + lr) * BK + kk + lk];
#pragma unroll
            for (int m = 0; m < 4; ++m)
#pragma unroll
                for (int n = 0; n < 4; ++n)
                    acc[m][n] = __builtin_amdgcn_mfma_f32_16x16x32_bf16(af[m], bfr[n],
                                                                        acc[m][n], 0, 0, 0);
        }
        __syncthreads();
    }

    const int cr = (l >> 4) * 4;
    const bool safe = ((long long)(bm + BM) * NDIM) <= out_elems;
    if (safe) {
#pragma unroll
        for (int m = 0; m < 4; ++m) {
            int grow = bm + wm + m * 16 + cr;
#pragma unroll
            for (int j = 0; j < 4; ++j) {
                float* cp = C + (size_t)(grow + j) * NDIM + bn + wn + lr;
#pragma unroll
                for (int n = 0; n < 4; ++n)
                    cp[n * 16] = acc[m][n][j];
            }
        }
    } else {
        for (int m = 0; m < 4; ++m) {
            int grow = bm + wm + m * 16 + cr;
            for (int j = 0; j < 4; ++j) {
                long long base = (long long)(grow + j) * NDIM + bn + wn + lr;
                for (int n = 0; n < 4; ++n)
                    if (base + n * 16 < out_elems) C[base + n * 16] = acc[m][n][j];
            }
        }
    }
}

// ---- fp32 fallback (only if ws too small) ----
__global__ void dft_naive(const float* __restrict__ x, const float* __restrict__ wsin,
                          const float* __restrict__ wcos, float* __restrict__ out,
                          long long out_elems, int real_only) {
    __shared__ float xs[K_DIM];
    int row = blockIdx.x;
    const float* xr = x + (size_t)row * K_DIM;
    for (int i = threadIdx.x; i < K_DIM; i += blockDim.x) xs[i] = xr[i];
    __syncthreads();
    for (int k = threadIdx.x; k < K_DIM; k += blockDim.x) {
        const float* wc = wcos + (size_t)k * K_DIM;
        float re = 0.f;
        if (real_only) {
            for (int s = 0; s < K_DIM; ++s) re += xs[s] * wc[s];
            long long o = (long long)row * K_DIM + k;
            if (o < out_elems) out[o] = re;
        } else {
            const float* ws = wsin + (size_t)k * K_DIM;
            float im = 0.f;
            for (int s = 0; s < K_DIM; ++s) { re += xs[s] * wc[s]; im += xs[s] * ws[s]; }
            long long o = ((long long)row * K_DIM + k) * 2;
            if (o + 1 < out_elems) { out[o] = re; out[o + 1] = -im; }
        }
    }
}

extern "C" void kernel_launch(void* const* d_in, const int* in_sizes, int n_in,
                              void* d_out, int out_size, void* d_ws, size_t ws_size,
                              hipStream_t stream) {
    const float* x    = (const float*)d_in[0];
    const float* wsin = (const float*)d_in[1];
    const float* wcos = (const float*)d_in[2];
    float* out = (float*)d_out;

    const int real_only = (out_size == M_TOT * 1024);
    const size_t need = (size_t)M_TOT * K_DIM * 2 + (size_t)2048 * K_DIM * 2;

    if (ws_size >= need) {
        uint16_t* xb = (uint16_t*)d_ws;
        uint16_t* Wb = xb + (size_t)M_TOT * K_DIM;
        if (real_only) {
            build_wc_kernel<<<512, 256, 0, stream>>>(wcos, Wb);
            dft_gemm256f<1024><<<(M_TOT / 256) * (1024 / 256), 512, 0, stream>>>(
                x, Wb, out, (long long)out_size);
        } else {
            cvt_x_kernel<<<2048, 256, 0, stream>>>(x, xb);
            build_w_kernel<<<512, 256, 0, stream>>>(wsin, wcos, Wb);
            dft_gemm128<2048><<<128 * 16, 256, 0, stream>>>(xb, Wb, out, (long long)out_size);
        }
    } else {
        dft_naive<<<M_TOT, 256, 0, stream>>>(x, wsin, wcos, out, (long long)out_size,
                                             real_only);
    }
}

// Round 9
// 51.531 us; speedup vs baseline: 1.6967x; 1.0228x over previous
//
#include <hip/hip_runtime.h>
#include <stdint.h>

#define K_DIM 1024
#define M_TOT 16384
#define BM 128
#define BN 128
#define BK 64

typedef __attribute__((ext_vector_type(8))) short bf16x8;
typedef __attribute__((ext_vector_type(4))) float f32x4;
typedef __attribute__((ext_vector_type(8))) unsigned short u16x8;

__device__ inline uint16_t f2bf(float f) {
    union { float f; uint32_t u; } v; v.f = f;
    return (uint16_t)((v.u + 0x7fffu + ((v.u >> 16) & 1u)) >> 16);
}

// ---- x (16M f32) -> bf16 (only used by the 2048 fallback path) ----
__global__ void cvt_x_kernel(const float* __restrict__ x, uint16_t* __restrict__ xb) {
    const size_t n8 = (size_t)M_TOT * K_DIM / 8;
    for (size_t i = (size_t)blockIdx.x * blockDim.x + threadIdx.x; i < n8;
         i += (size_t)gridDim.x * blockDim.x) {
        const float4* s = (const float4*)x + i * 2;
        float4 a = s[0], b = s[1];
        u16x8 v;
        v[0] = f2bf(a.x); v[1] = f2bf(a.y); v[2] = f2bf(a.z); v[3] = f2bf(a.w);
        v[4] = f2bf(b.x); v[5] = f2bf(b.y); v[6] = f2bf(b.z); v[7] = f2bf(b.w);
        *(u16x8*)(xb + i * 8) = v;
    }
}

// ---- real-only weights: Wc[k][s] = cos(2*pi*k*s/N), bf16 [1024][1024] ----
__global__ void build_wc_kernel(const float* __restrict__ wcos, uint16_t* __restrict__ W) {
    int i = blockIdx.x * blockDim.x + threadIdx.x;
    int k = i >> 7;
    int sc = (i & 127) * 8;
    const float4* c = (const float4*)(wcos + (size_t)k * K_DIM + sc);
    float4 c0 = c[0], c1 = c[1];
    u16x8 vc;
    vc[0] = f2bf(c0.x); vc[1] = f2bf(c0.y); vc[2] = f2bf(c0.z); vc[3] = f2bf(c0.w);
    vc[4] = f2bf(c1.x); vc[5] = f2bf(c1.y); vc[6] = f2bf(c1.z); vc[7] = f2bf(c1.w);
    *(u16x8*)(W + (size_t)k * K_DIM + sc) = vc;
}

// ---- interleaved weights (fallback path): W[2k][s]=cos, W[2k+1][s]=-sin ----
__global__ void build_w_kernel(const float* __restrict__ wsin, const float* __restrict__ wcos,
                               uint16_t* __restrict__ W) {
    int i = blockIdx.x * blockDim.x + threadIdx.x;
    int k = i >> 7;
    int sc = (i & 127) * 8;
    const float4* c = (const float4*)(wcos + (size_t)k * K_DIM + sc);
    const float4* s = (const float4*)(wsin + (size_t)k * K_DIM + sc);
    float4 c0 = c[0], c1 = c[1], s0 = s[0], s1 = s[1];
    u16x8 vc, vs;
    vc[0] = f2bf(c0.x); vc[1] = f2bf(c0.y); vc[2] = f2bf(c0.z); vc[3] = f2bf(c0.w);
    vc[4] = f2bf(c1.x); vc[5] = f2bf(c1.y); vc[6] = f2bf(c1.z); vc[7] = f2bf(c1.w);
    vs[0] = f2bf(-s0.x); vs[1] = f2bf(-s0.y); vs[2] = f2bf(-s0.z); vs[3] = f2bf(-s0.w);
    vs[4] = f2bf(-s1.x); vs[5] = f2bf(-s1.y); vs[6] = f2bf(-s1.z); vs[7] = f2bf(-s1.w);
    *(u16x8*)(W + (size_t)(2 * k) * K_DIM + sc) = vc;
    *(u16x8*)(W + (size_t)(2 * k + 1) * K_DIM + sc) = vs;
}

// =====================================================================
// Fused-cvt 256x256 bf16 MFMA GEMM, MINIMAL-SYNC schedule:
//   Within a K-tile all reads hit buf[c], all writes hit buf[1-c] ->
//   exactly ONE collective barrier per K-tile (was 8).  Counted waits:
//   issue B-DMA(kt+1) BEFORE A-loads(kt+2) so the boundary vmcnt(8)
//   drains only B; A loads stay in flight across the barrier (never
//   vmcnt(0) in the loop).  Waves free-run inside the tile; compiler
//   emits precise lgkmcnt for frag reads (m97 r109).
// =====================================================================
template <int NDIM>
__global__ __launch_bounds__(512, 2) void dft_gemm256f(const float* __restrict__ X,
                                                       const uint16_t* __restrict__ Bw,
                                                       float* __restrict__ C,
                                                       long long out_elems) {
    constexpr int BM2 = 256, BN2 = 256, BK2 = 64;
    constexpr int NT = NDIM / BN2;
    constexpr int NKT = K_DIM / BK2;
    __shared__ uint16_t lds[2][2][BM2 * BK2];   // [dbuf][A=0/B=1][256*64]

    const int t = threadIdx.x;
    const int l = t & 63;
    const int wid = t >> 6;
    const int wr = wid >> 2;      // M half
    const int wc = wid & 3;       // N quarter
    const int lr = l & 15;
    const int lhi = l >> 4;
    const int xr7 = lr & 7;

    // T1: bijective XCD swizzle (grid % 8 == 0)
    int bid = blockIdx.x;
    {
        int nwg = gridDim.x;
        if ((nwg & 7) == 0) { int q = nwg >> 3; bid = (bid & 7) * q + (bid >> 3); }
    }
    const int bm = (bid / NT) * BM2;
    const int bn = (bid % NT) * BN2;

    // thread t stages rows r0 + i*64 (i=0..3), slot sl (8 elems = 16 B)
    const int r0 = t >> 3, sl = t & 7;
    const float* gA0 = X + (size_t)(bm + r0) * K_DIM + sl * 8;                  // linear src
    const int wA0 = (r0 * 8 + (sl ^ (r0 & 7))) * 16;                            // swz LDS byte
    const uint16_t* gB0 = Bw + (size_t)(bn + r0) * K_DIM + (sl ^ (r0 & 7)) * 8; // pre-swz src
    const int ldsB0 = (t & ~63) * 16;                                           // wave-uniform

    float4 ra[4][2];   // in-flight A f32 (one K-tile's worth per thread)

    auto loadA_all = [&](int kt) {
        const int k0 = kt * BK2;
#pragma unroll
        for (int i = 0; i < 4; ++i) {
            const float* p = gA0 + (size_t)i * 64 * K_DIM + k0;
            ra[i][0] = *(const float4*)p;
            ra[i][1] = *(const float4*)(p + 4);
        }
    };
    auto stageB_all = [&](int d, int kt) {
        const int k0 = kt * BK2;
#pragma unroll
        for (int i = 0; i < 4; ++i)
            __builtin_amdgcn_global_load_lds(
                (const __attribute__((address_space(1))) void*)(gB0 + (size_t)i * 64 * K_DIM + k0),
                (__attribute__((address_space(3))) void*)((char*)&lds[d][1][0] + ldsB0 + i * 8192),
                16, 0, 0);
    };
    auto writeA_all = [&](int d) {
#pragma unroll
        for (int i = 0; i < 4; ++i) {
            union { u16x8 v; uint32_t w[4]; } u;
            asm("v_cvt_pk_bf16_f32 %0, %1, %2" : "=v"(u.w[0]) : "v"(ra[i][0].x), "v"(ra[i][0].y));
            asm("v_cvt_pk_bf16_f32 %0, %1, %2" : "=v"(u.w[1]) : "v"(ra[i][0].z), "v"(ra[i][0].w));
            asm("v_cvt_pk_bf16_f32 %0, %1, %2" : "=v"(u.w[2]) : "v"(ra[i][1].x), "v"(ra[i][1].y));
            asm("v_cvt_pk_bf16_f32 %0, %1, %2" : "=v"(u.w[3]) : "v"(ra[i][1].z), "v"(ra[i][1].w));
            *(u16x8*)((char*)&lds[d][0][0] + wA0 + i * 8192) = u.v;
        }
    };
    // swizzled fragment read: element = row*64 + ((slot ^ (row&7))*8)
    auto loadFrag = [&](const uint16_t* base, int row, int kk) -> bf16x8 {
        int s = (kk >> 3) + lhi;
        return *(const bf16x8*)(base + row * 64 + ((s ^ xr7) * 8));
    };

    f32x4 acc[8][4] = {};

    // ---- prologue: buf0 fully staged (A(0) written, B(0) landed); A(1) in flight ----
    loadA_all(0);                            // 8 VMEM
    stageB_all(0, 0);                        // 4 VMEM
    __builtin_amdgcn_sched_barrier(0);
    writeA_all(0);                           // compiler inserts counted wait on A(0)
    __builtin_amdgcn_sched_barrier(0);
    loadA_all(1);                            // 8 VMEM (A for kt=0's publish)
    __builtin_amdgcn_sched_barrier(0);
    asm volatile("s_waitcnt vmcnt(8)" ::: "memory");   // B(0) landed; A(1) in flight
    asm volatile("s_waitcnt lgkmcnt(0)" ::: "memory"); // A(0) ds_writes visible
    __builtin_amdgcn_s_barrier();
    __builtin_amdgcn_sched_barrier(0);

    // ---- main loop: ONE barrier per K-tile ----
    for (int kt = 0; kt < NKT; ++kt) {
        const int cc = kt & 1;
        const uint16_t* bA = &lds[cc][0][0];
        const uint16_t* bB = &lds[cc][1][0];
        int ktn = kt + 1;  if (ktn >= NKT) ktn -= NKT;    // wrap: uniform counts
        int ktnn = kt + 2; if (ktnn >= NKT) ktnn -= NKT;

        // top: publish A(kt+1) -> buf[1-cc]; issue B(kt+1) (oldest), A(kt+2) (newest)
        writeA_all(1 - cc);
        __builtin_amdgcn_sched_barrier(0);
        stageB_all(1 - cc, ktn);
        loadA_all(ktnn);
        __builtin_amdgcn_sched_barrier(0);

        // free-run compute on buf[cc]: 24 ds_read_b128 + 64 MFMA, no barriers
#pragma unroll
        for (int ks = 0; ks < 2; ++ks) {
            const int kk = ks * 32;
            bf16x8 bfr[4];
#pragma unroll
            for (int n = 0; n < 4; ++n) bfr[n] = loadFrag(bB, wc * 64 + n * 16 + lr, kk);
#pragma unroll
            for (int h = 0; h < 2; ++h) {
                bf16x8 af[4];
#pragma unroll
                for (int m = 0; m < 4; ++m)
                    af[m] = loadFrag(bA, wr * 128 + h * 64 + m * 16 + lr, kk);
                __builtin_amdgcn_s_setprio(1);
#pragma unroll
                for (int m = 0; m < 4; ++m)
#pragma unroll
                    for (int n = 0; n < 4; ++n)
                        acc[h * 4 + m][n] = __builtin_amdgcn_mfma_f32_16x16x32_bf16(
                            af[m], bfr[n], acc[h * 4 + m][n], 0, 0, 0);
                __builtin_amdgcn_s_setprio(0);
            }
        }

        // boundary: B(kt+1) landed (oldest 4 of 12); A(kt+2) stays in flight;
        // this wave's ds_reads of buf[cc] + ds_writes of buf[1-cc] retired.
        __builtin_amdgcn_sched_barrier(0);
        asm volatile("s_waitcnt vmcnt(8)" ::: "memory");
        asm volatile("s_waitcnt lgkmcnt(0)" ::: "memory");
        __builtin_amdgcn_s_barrier();
        __builtin_amdgcn_sched_barrier(0);
    }

    // ---- epilogue: C/D layout (m89): col = lane&15, row = (lane>>4)*4 + j ----
    const int cr = lhi * 4;
    const bool safe = ((long long)(bm + BM2) * NDIM) <= out_elems;
    if (safe) {
#pragma unroll
        for (int m = 0; m < 8; ++m) {
            int grow = bm + wr * 128 + m * 16 + cr;
#pragma unroll
            for (int j = 0; j < 4; ++j) {
                float* cp = C + (size_t)(grow + j) * NDIM + bn + wc * 64 + lr;
#pragma unroll
                for (int n = 0; n < 4; ++n)
                    cp[n * 16] = acc[m][n][j];
            }
        }
    } else {
        for (int m = 0; m < 8; ++m) {
            int grow = bm + wr * 128 + m * 16 + cr;
            for (int j = 0; j < 4; ++j) {
                long long base = (long long)(grow + j) * NDIM + bn + wc * 64 + lr;
                for (int n = 0; n < 4; ++n)
                    if (base + n * 16 < out_elems) C[base + n * 16] = acc[m][n][j];
            }
        }
    }
}

// ---- 128x128 gload_lds GEMM (fallback for the interleaved/2048 path) ----
template <int NDIM>
__global__ __launch_bounds__(256) void dft_gemm128(const uint16_t* __restrict__ A,
                                                   const uint16_t* __restrict__ B,
                                                   float* __restrict__ C,
                                                   long long out_elems) {
    constexpr int NT = NDIM / BN;
    __shared__ uint16_t As[BM * BK];
    __shared__ uint16_t Bs[BN * BK];

    const int t = threadIdx.x;
    const int l = t & 63;
    const int w = t >> 6;

    int bid = blockIdx.x;
    {
        int nwg = gridDim.x;
        if ((nwg & 7) == 0) { int q = nwg >> 3; bid = (bid & 7) * q + (bid >> 3); }
    }
    const int bm = (bid / NT) * BM;
    const int bn = (bid % NT) * BN;

    const uint16_t* gA[4];
    const uint16_t* gB[4];
    int ldsOff[4];
#pragma unroll
    for (int i = 0; i < 4; ++i) {
        int chunk = i * 256 + t;
        int row = chunk >> 3;
        int cc = (chunk & 7) * 8;
        gA[i] = A + (size_t)(bm + row) * K_DIM + cc;
        gB[i] = B + (size_t)(bn + row) * K_DIM + cc;
        ldsOff[i] = (i * 256 + (t & 192)) * 16;
    }

    const int wm = ((w >> 1) & 1) * 64;
    const int wn = (w & 1) * 64;
    const int lr = l & 15;
    const int lk = (l >> 4) * 8;

    f32x4 acc[4][4] = {};

    for (int k0 = 0; k0 < K_DIM; k0 += BK) {
#pragma unroll
        for (int i = 0; i < 4; ++i)
            __builtin_amdgcn_global_load_lds(
                (const __attribute__((address_space(1))) void*)(gA[i] + k0),
                (__attribute__((address_space(3))) void*)((char*)As + ldsOff[i]), 16, 0, 0);
#pragma unroll
        for (int i = 0; i < 4; ++i)
            __builtin_amdgcn_global_load_lds(
                (const __attribute__((address_space(1))) void*)(gB[i] + k0),
                (__attribute__((address_space(3))) void*)((char*)Bs + ldsOff[i]), 16, 0, 0);
        __syncthreads();
#pragma unroll
        for (int kk = 0; kk < BK; kk += 32) {
            bf16x8 af[4], bfr[4];
#pragma unroll
            for (int m = 0; m < 4; ++m)
                af[m] = *(const bf16x8*)&As[(wm + m * 16 + lr) * BK + kk + lk];
#pragma unroll
            for (int n = 0; n < 4; ++n)
                bfr[n] = *(const bf16x8*)&Bs[(wn + n * 16 + lr) * BK + kk + lk];
#pragma unroll
            for (int m = 0; m < 4; ++m)
#pragma unroll
                for (int n = 0; n < 4; ++n)
                    acc[m][n] = __builtin_amdgcn_mfma_f32_16x16x32_bf16(af[m], bfr[n],
                                                                        acc[m][n], 0, 0, 0);
        }
        __syncthreads();
    }

    const int cr = (l >> 4) * 4;
    const bool safe = ((long long)(bm + BM) * NDIM) <= out_elems;
    if (safe) {
#pragma unroll
        for (int m = 0; m < 4; ++m) {
            int grow = bm + wm + m * 16 + cr;
#pragma unroll
            for (int j = 0; j < 4; ++j) {
                float* cp = C + (size_t)(grow + j) * NDIM + bn + wn + lr;
#pragma unroll
                for (int n = 0; n < 4; ++n)
                    cp[n * 16] = acc[m][n][j];
            }
        }
    } else {
        for (int m = 0; m < 4; ++m) {
            int grow = bm + wm + m * 16 + cr;
            for (int j = 0; j < 4; ++j) {
                long long base = (long long)(grow + j) * NDIM + bn + wn + lr;
                for (int n = 0; n < 4; ++n)
                    if (base + n * 16 < out_elems) C[base + n * 16] = acc[m][n][j];
            }
        }
    }
}

// ---- fp32 fallback (only if ws too small) ----
__global__ void dft_naive(const float* __restrict__ x, const float* __restrict__ wsin,
                          const float* __restrict__ wcos, float* __restrict__ out,
                          long long out_elems, int real_only) {
    __shared__ float xs[K_DIM];
    int row = blockIdx.x;
    const float* xr = x + (size_t)row * K_DIM;
    for (int i = threadIdx.x; i < K_DIM; i += blockDim.x) xs[i] = xr[i];
    __syncthreads();
    for (int k = threadIdx.x; k < K_DIM; k += blockDim.x) {
        const float* wc = wcos + (size_t)k * K_DIM;
        float re = 0.f;
        if (real_only) {
            for (int s = 0; s < K_DIM; ++s) re += xs[s] * wc[s];
            long long o = (long long)row * K_DIM + k;
            if (o < out_elems) out[o] = re;
        } else {
            const float* ws = wsin + (size_t)k * K_DIM;
            float im = 0.f;
            for (int s = 0; s < K_DIM; ++s) { re += xs[s] * wc[s]; im += xs[s] * ws[s]; }
            long long o = ((long long)row * K_DIM + k) * 2;
            if (o + 1 < out_elems) { out[o] = re; out[o + 1] = -im; }
        }
    }
}

extern "C" void kernel_launch(void* const* d_in, const int* in_sizes, int n_in,
                              void* d_out, int out_size, void* d_ws, size_t ws_size,
                              hipStream_t stream) {
    const float* x    = (const float*)d_in[0];
    const float* wsin = (const float*)d_in[1];
    const float* wcos = (const float*)d_in[2];
    float* out = (float*)d_out;

    const int real_only = (out_size == M_TOT * 1024);
    const size_t need = (size_t)M_TOT * K_DIM * 2 + (size_t)2048 * K_DIM * 2;

    if (ws_size >= need) {
        uint16_t* xb = (uint16_t*)d_ws;
        uint16_t* Wb = xb + (size_t)M_TOT * K_DIM;
        if (real_only) {
            build_wc_kernel<<<512, 256, 0, stream>>>(wcos, Wb);
            dft_gemm256f<1024><<<(M_TOT / 256) * (1024 / 256), 512, 0, stream>>>(
                x, Wb, out, (long long)out_size);
        } else {
            cvt_x_kernel<<<2048, 256, 0, stream>>>(x, xb);
            build_w_kernel<<<512, 256, 0, stream>>>(wsin, wcos, Wb);
            dft_gemm128<2048><<<128 * 16, 256, 0, stream>>>(xb, Wb, out, (long long)out_size);
        }
    } else {
        dft_naive<<<M_TOT, 256, 0, stream>>>(x, wsin, wcos, out, (long long)out_size,
                                             real_only);
    }
}